// Round 7
// baseline (238.116 us; speedup 1.0000x reference)
//
#include <hip/hip_runtime.h>
#include <math.h>

#define NE     50000
#define NNODE  10000
#define HDIM   128
#define GBIN   2048
#define NLUT   2049          // GBIN+1 rows
#define NC     4160          // 576 + 3584
#define NC1    576
#define NCHMAX 2834          // 2048 + ceil(50000/64)

typedef _Float16 h2 __attribute__((ext_vector_type(2)));
typedef _Float16 h4 __attribute__((ext_vector_type(4)));
typedef _Float16 h8 __attribute__((ext_vector_type(8)));

// constants
#define SQ3C        1.7320508075688772f
#define INV_SQ3     0.5773502691896258f
#define C0_1F       0.20412414523193154f   // 1/sqrt(24)
#define C1_1_OS3F   0.20412414523193154f   // sqrt(3/24)/sqrt(3)
#define C0_2F       0.05590169943749474f   // 1/sqrt(320)
#define C1_2_OS3F   0.0625f                // sqrt(3/256)/sqrt(3)
#define INV_SQRT_H  0.08838834764831845f   // 1/sqrt(128)
#define DELTA       (5.0f/2048.0f)
#define INV_DELTA   409.6f
#define STEP_INV    (51.0f/5.0f)

// ---------------- K1: LUT build (fp16 output) ----------------
__global__ __launch_bounds__(256) void k_lut(
    const float* __restrict__ lw1, const float* __restrict__ lw2,
    const float* __restrict__ rw1, const float* __restrict__ rw2,
    const float actc, const float K0C, _Float16* __restrict__ lut) {
  __shared__ float Hs[256][20];
  const int pb = blockIdx.x;
  const int t  = threadIdx.x;
  {
    const int which = t >> 7, hc = t & 127;
    const float* __restrict__ w1 = which ? rw1 : lw1;
#pragma unroll
    for (int m = 0; m < 16; ++m) {
      const int g = pb * 16 + m;
      float h = 0.f;
      if (g <= GBIN) {
        const float d  = (float)g * DELTA;
        const float tt = d * STEP_INV;
        const int   i0 = (int)floorf(tt);
        float z = 0.f;
#pragma unroll
        for (int k = 0; k < 2; ++k) {
          const int ii = i0 + k;
          if (ii >= 1 && ii <= 50) {
            const float diff = tt - (float)ii;
            const float a = diff + 1.f, b = 1.f - diff;
            if (a > 0.f && b > 0.f) {
              const float val = K0C * __expf(-1.f / a - 1.f / b);
              z += val * w1[(ii - 1) * HDIM + hc];
            }
          }
        }
        h = actc * z / (1.f + __expf(-z)) * INV_SQRT_H;
      }
      Hs[t][m] = h;
    }
  }
  __syncthreads();

  const int n0 = blockIdx.y * 1024 + t * 4;
  if (n0 >= NC) return;
  const int isrec = (n0 >= NC1);
  const float* __restrict__ w2 = isrec ? (rw2 + (n0 - NC1)) : (lw2 + n0);
  const int stride = isrec ? 3584 : 576;
  const int hbase  = isrec ? 128 : 0;

  float acc[4][16];
#pragma unroll
  for (int c = 0; c < 4; ++c)
#pragma unroll
    for (int m = 0; m < 16; ++m) acc[c][m] = 0.f;

#pragma unroll 2
  for (int h = 0; h < HDIM; ++h) {
    const float4 wv = *(const float4*)(w2 + (size_t)h * stride);
    const float* hp = &Hs[hbase + h][0];
    const float4 m0 = *(const float4*)(hp);
    const float4 m1 = *(const float4*)(hp + 4);
    const float4 m2 = *(const float4*)(hp + 8);
    const float4 m3 = *(const float4*)(hp + 12);
    float hm[16];
    hm[0]=m0.x; hm[1]=m0.y; hm[2]=m0.z; hm[3]=m0.w;
    hm[4]=m1.x; hm[5]=m1.y; hm[6]=m1.z; hm[7]=m1.w;
    hm[8]=m2.x; hm[9]=m2.y; hm[10]=m2.z; hm[11]=m2.w;
    hm[12]=m3.x; hm[13]=m3.y; hm[14]=m3.z; hm[15]=m3.w;
    float wc[4]; wc[0]=wv.x; wc[1]=wv.y; wc[2]=wv.z; wc[3]=wv.w;
#pragma unroll
    for (int c = 0; c < 4; ++c)
#pragma unroll
      for (int m = 0; m < 16; ++m) acc[c][m] += wc[c] * hm[m];
  }

#pragma unroll
  for (int m = 0; m < 16; ++m) {
    const int g = pb * 16 + m;
    if (g <= GBIN) {
      h4 o;
      o[0] = (_Float16)acc[0][m]; o[1] = (_Float16)acc[1][m];
      o[2] = (_Float16)acc[2][m]; o[3] = (_Float16)acc[3][m];
      *(h4*)(lut + (size_t)g * NC + n0) = o;
    }
  }
}

// ---------------- K2: per-edge bin/frac + histogram; zero inactive outputs ----------------
__global__ void k_edge(const int* __restrict__ ei, const float* __restrict__ pos,
                       float* __restrict__ out, int* __restrict__ bin_e,
                       float* __restrict__ f_e, int* __restrict__ cnt) {
  const int e = blockIdx.x * 256 + threadIdx.x;
  if (e >= NE) return;
  const int rec = ei[e], lig = ei[NE + e];
  const float ax = pos[lig * 3 + 0] - pos[rec * 3 + 0];
  const float ay = pos[lig * 3 + 1] - pos[rec * 3 + 1];
  const float az = pos[lig * 3 + 2] - pos[rec * 3 + 2];
  const float d = sqrtf(ax * ax + ay * ay + az * az);
  if (d > 0.f && d < 5.0f) {
    const float tf = d * INV_DELTA;
    int b = (int)tf;
    if (b > GBIN - 1) b = GBIN - 1;
    bin_e[e] = b;
    f_e[e] = tf - (float)b;
    atomicAdd(&cnt[b], 1);
  } else {
    bin_e[e] = -1;
    float* o = out + (size_t)e * 20;
#pragma unroll
    for (int i2 = 0; i2 < 20; ++i2) o[i2] = 0.f;
  }
}

// ---------------- K3a: scan + chunk-table emission (single block) ----------------
__global__ void k_scan(const int* __restrict__ cnt, int* __restrict__ offs,
                       int* __restrict__ woff, int* __restrict__ chunk_bin,
                       int* __restrict__ chunk_start, int* __restrict__ nch) {
  __shared__ int lds[256];
  const int t = threadIdx.x;
  int loc[8];
  int s = 0;
#pragma unroll
  for (int i = 0; i < 8; ++i) { loc[i] = cnt[t * 8 + i]; s += loc[i]; }
  lds[t] = s;
  __syncthreads();
  for (int o = 1; o < 256; o <<= 1) {
    int v = 0;
    if (t >= o) v = lds[t - o];
    __syncthreads();
    lds[t] += v;
    __syncthreads();
  }
  int run = lds[t] - s;
  int runs[8];
#pragma unroll
  for (int i = 0; i < 8; ++i) {
    runs[i] = run;
    offs[t * 8 + i] = run;
    woff[t * 8 + i] = run;
    run += loc[i];
  }
  if (t == 255) offs[GBIN] = run;

  // second scan: chunk counts (ceil(count/64) per bin)
  int ccnt[8];
  int csum = 0;
#pragma unroll
  for (int i = 0; i < 8; ++i) { ccnt[i] = (loc[i] + 63) >> 6; csum += ccnt[i]; }
  __syncthreads();
  lds[t] = csum;
  __syncthreads();
  for (int o = 1; o < 256; o <<= 1) {
    int v = 0;
    if (t >= o) v = lds[t - o];
    __syncthreads();
    lds[t] += v;
    __syncthreads();
  }
  int crun = lds[t] - csum;
#pragma unroll
  for (int i = 0; i < 8; ++i) {
    for (int c = 0; c < ccnt[i]; ++c) {
      chunk_bin[crun]   = t * 8 + i;
      chunk_start[crun] = runs[i] + c * 64;
      ++crun;
    }
  }
  if (t == 255) nch[0] = lds[255];
}

// ---------------- K3b: counting-sort scatter ----------------
__global__ void k_scatter(const int* __restrict__ bin_e, int* __restrict__ woff,
                          int* __restrict__ sorted) {
  const int e = blockIdx.x * 256 + threadIdx.x;
  if (e >= NE) return;
  const int b = bin_e[e];
  if (b >= 0) {
    const int p = atomicAdd(&woff[b], 1);
    sorted[p] = e;
  }
}

// ---------------- K4: epilogue: one 64-edge chunk per 256-thread block ----------------
// fp16 LUT rows staged RAW into LDS (16.6 KB); convert at use (fp32 FMA accumulate).
// 4 lanes per edge; layer 1 output-split + quad allgather; layer 2 v-split (v = vv*4+s),
// two row passes with weights (1-f), f.
__global__ __launch_bounds__(256) void k_epi(
    const _Float16* __restrict__ lut, const int* __restrict__ chunk_bin,
    const int* __restrict__ chunk_start, const int* __restrict__ offs,
    const int* __restrict__ sorted, const float* __restrict__ f_e,
    const int* __restrict__ ei, const float* __restrict__ pos,
    const float* __restrict__ x, float* __restrict__ out,
    const int* __restrict__ nch) {
  __shared__ h8 Wl8[1040];             // 2 rows x 4160 fp16 = 16640 B
  const int bid = blockIdx.x;
  if (bid >= nch[0]) return;
  const int b     = chunk_bin[bid];
  const int start = chunk_start[bid];
  const int end0  = offs[b + 1];
  const int end   = (start + 64 < end0) ? (start + 64) : end0;
  const int tid = threadIdx.x;
  {  // raw copy: 1040 x (16B global load -> 16B ds_write)
    const h8* src = (const h8*)(lut + (size_t)b * NC);
    for (int i = tid; i < 1040; i += 256) Wl8[i] = src[i];
  }
  __syncthreads();
  const _Float16* __restrict__ W0 = (const _Float16*)Wl8;
  const _Float16* __restrict__ W1 = W0 + NC;
  const int s  = tid & 3;
  const int qb = (tid & 63) & ~3;
  const int slot = start + (tid >> 2);
  if (slot >= end) return;

  const int e = sorted[slot];
  const float f = f_e[e];
  const int rec = ei[e], lig = ei[NE + e];
  const float ax = pos[lig * 3 + 0] - pos[rec * 3 + 0];
  const float ay = pos[lig * 3 + 1] - pos[rec * 3 + 1];
  const float az = pos[lig * 3 + 2] - pos[rec * 3 + 2];
  const float d = sqrtf(ax * ax + ay * ay + az * az);
  const float inv = SQ3C / fmaxf(d, 1e-12f);
  const float sh0 = ax * inv, sh1 = ay * inv, sh2 = az * inv;

  // ---- lig features ----
  float s1[16], v1[24];
  {
    const float4* xl = (const float4*)(x + (size_t)lig * 40);
#pragma unroll
    for (int j = 0; j < 4; ++j) {
      float4 v = xl[j];
      s1[j * 4 + 0] = v.x; s1[j * 4 + 1] = v.y; s1[j * 4 + 2] = v.z; s1[j * 4 + 3] = v.w;
    }
#pragma unroll
    for (int j = 0; j < 6; ++j) {
      float4 v = xl[4 + j];
      v1[j * 4 + 0] = v.x; v1[j * 4 + 1] = v.y; v1[j * 4 + 2] = v.z; v1[j * 4 + 3] = v.w;
    }
  }
  float vs[8];
#pragma unroll
  for (int u = 0; u < 8; ++u)
    vs[u] = (v1[u * 3] * sh0 + v1[u * 3 + 1] * sh1 + v1[u * 3 + 2] * sh2) * INV_SQ3;

  // ---- layer 1: sa (lane owns w = 4s..4s+3) ----
  float A0[4] = {0.f, 0.f, 0.f, 0.f}, A1[4] = {0.f, 0.f, 0.f, 0.f};
#pragma unroll
  for (int u = 0; u < 16; ++u) {   // W000 @ 0: [u:16][w:16]
    h4 w0 = *(const h4*)(W0 + u * 16 + s * 4);
    h4 w1 = *(const h4*)(W1 + u * 16 + s * 4);
    const float su = s1[u];
    A0[0] += (float)w0[0] * su; A0[1] += (float)w0[1] * su;
    A0[2] += (float)w0[2] * su; A0[3] += (float)w0[3] * su;
    A1[0] += (float)w1[0] * su; A1[1] += (float)w1[1] * su;
    A1[2] += (float)w1[2] * su; A1[3] += (float)w1[3] * su;
  }
#pragma unroll
  for (int u = 0; u < 8; ++u) {    // W110 @ 448: [u:8][w:16]
    h4 w0 = *(const h4*)(W0 + 448 + u * 16 + s * 4);
    h4 w1 = *(const h4*)(W1 + 448 + u * 16 + s * 4);
    const float su = vs[u];
    A0[0] += (float)w0[0] * su; A0[1] += (float)w0[1] * su;
    A0[2] += (float)w0[2] * su; A0[3] += (float)w0[3] * su;
    A1[0] += (float)w1[0] * su; A1[1] += (float)w1[1] * su;
    A1[2] += (float)w1[2] * su; A1[3] += (float)w1[3] * su;
  }
  const float sa0 = C0_1F * (A0[0] + f * (A1[0] - A0[0]));
  const float sa1 = C0_1F * (A0[1] + f * (A1[1] - A0[1]));
  const float sa2 = C0_1F * (A0[2] + f * (A1[2] - A0[2]));
  const float sa3 = C0_1F * (A0[3] + f * (A1[3] - A0[3]));

  // ---- layer 1: va (lane owns w = 2s, 2s+1) ----
  float vaA0, vaA1, vaA2, vaB0, vaB1, vaB2;
  {
    float cA0 = 0.f, cB0 = 0.f, cA1 = 0.f, cB1 = 0.f;
#pragma unroll
    for (int u = 0; u < 16; ++u) {  // W011 @ 256: [u:16][w:8]
      h2 w0 = *(const h2*)(W0 + 256 + u * 8 + s * 2);
      h2 w1 = *(const h2*)(W1 + 256 + u * 8 + s * 2);
      const float su = s1[u];
      cA0 += (float)w0[0] * su; cB0 += (float)w0[1] * su;
      cA1 += (float)w1[0] * su; cB1 += (float)w1[1] * su;
    }
    float tA0x=0.f,tA0y=0.f,tA0z=0.f, tB0x=0.f,tB0y=0.f,tB0z=0.f;
    float tA1x=0.f,tA1y=0.f,tA1z=0.f, tB1x=0.f,tB1y=0.f,tB1z=0.f;
#pragma unroll
    for (int u = 0; u < 8; ++u) {   // W101 @ 384: [u:8][w:8]
      h2 w0 = *(const h2*)(W0 + 384 + u * 8 + s * 2);
      h2 w1 = *(const h2*)(W1 + 384 + u * 8 + s * 2);
      const float p0 = v1[u * 3], p1 = v1[u * 3 + 1], p2 = v1[u * 3 + 2];
      const float a0 = (float)w0[0], b0v = (float)w0[1];
      const float a1 = (float)w1[0], b1v = (float)w1[1];
      tA0x += a0 * p0; tA0y += a0 * p1; tA0z += a0 * p2;
      tB0x += b0v * p0; tB0y += b0v * p1; tB0z += b0v * p2;
      tA1x += a1 * p0; tA1y += a1 * p1; tA1z += a1 * p2;
      tB1x += b1v * p0; tB1y += b1v * p1; tB1z += b1v * p2;
    }
    const float cA = cA0 + f * (cA1 - cA0);
    const float cB = cB0 + f * (cB1 - cB0);
    vaA0 = C1_1_OS3F * (cA * sh0 + (tA0x + f * (tA1x - tA0x)));
    vaA1 = C1_1_OS3F * (cA * sh1 + (tA0y + f * (tA1y - tA0y)));
    vaA2 = C1_1_OS3F * (cA * sh2 + (tA0z + f * (tA1z - tA0z)));
    vaB0 = C1_1_OS3F * (cB * sh0 + (tB0x + f * (tB1x - tB0x)));
    vaB1 = C1_1_OS3F * (cB * sh1 + (tB0y + f * (tB1y - tB0y)));
    vaB2 = C1_1_OS3F * (cB * sh2 + (tB0z + f * (tB1z - tB0z)));
  }

  // ---- quad allgather ----
  float saF[16];
#pragma unroll
  for (int k = 0; k < 16; ++k) {
    const float v = ((k & 3) == 0) ? sa0 : ((k & 3) == 1) ? sa1 : ((k & 3) == 2) ? sa2 : sa3;
    saF[k] = __shfl(v, qb + (k >> 2), 64);
  }
  float vaF[24];
#pragma unroll
  for (int w = 0; w < 8; ++w) {
    const int src = qb + (w >> 1);
    const float x0 = (w & 1) ? vaB0 : vaA0;
    const float x1 = (w & 1) ? vaB1 : vaA1;
    const float x2 = (w & 1) ? vaB2 : vaA2;
    vaF[w * 3 + 0] = __shfl(x0, src, 64);
    vaF[w * 3 + 1] = __shfl(x1, src, 64);
    vaF[w * 3 + 2] = __shfl(x2, src, 64);
  }

  // ---- rec features: lane's v-subset ----
  const float* xr = x + (size_t)rec * 40;
  const float sbl0 = xr[s],      sbl1 = xr[4 + s];
  const float sbl2 = xr[8 + s],  sbl3 = xr[12 + s];
  const float vbA0 = xr[16 + s * 3 + 0], vbA1 = xr[16 + s * 3 + 1], vbA2 = xr[16 + s * 3 + 2];
  const float vbB0 = xr[16 + (s + 4) * 3 + 0], vbB1 = xr[16 + (s + 4) * 3 + 1], vbB2 = xr[16 + (s + 4) * 3 + 2];

  // ---- layer 2: two row passes ----
  float oe[20];
#pragma unroll
  for (int w = 0; w < 20; ++w) oe[w] = 0.f;
#pragma unroll
  for (int r = 0; r < 2; ++r) {
    const _Float16* __restrict__ Wr = r ? W1 : W0;
    const float cr = r ? f : (1.f - f);
    float so[8];
    float uo[12];
#pragma unroll
    for (int w = 0; w < 8; ++w) so[w] = 0.f;
#pragma unroll
    for (int w = 0; w < 12; ++w) uo[w] = 0.f;

    // W000 @ 576: [u:16][v:16][w:8], v = vv*4+s
#pragma unroll
    for (int u = 0; u < 16; ++u) {
      const float su = saF[u];
      const _Float16* rp = Wr + 576 + u * 128 + s * 8;
#pragma unroll
      for (int vv = 0; vv < 4; ++vv) {
        const float p = su * ((vv == 0) ? sbl0 : (vv == 1) ? sbl1 : (vv == 2) ? sbl2 : sbl3);
        h8 w = *(const h8*)(rp + vv * 32);
        so[0] += (float)w[0] * p; so[1] += (float)w[1] * p;
        so[2] += (float)w[2] * p; so[3] += (float)w[3] * p;
        so[4] += (float)w[4] * p; so[5] += (float)w[5] * p;
        so[6] += (float)w[6] * p; so[7] += (float)w[7] * p;
      }
    }
    // W110 @ 3648: [u:8][v:8][w:8], v = vv*4+s
#pragma unroll
    for (int u = 0; u < 8; ++u) {
      const float a0 = vaF[u * 3], a1 = vaF[u * 3 + 1], a2 = vaF[u * 3 + 2];
      const _Float16* rp = Wr + 3648 + u * 64 + s * 8;
#pragma unroll
      for (int vv = 0; vv < 2; ++vv) {
        const float b0v = vv ? vbB0 : vbA0;
        const float b1v = vv ? vbB1 : vbA1;
        const float b2v = vv ? vbB2 : vbA2;
        const float dd = (a0 * b0v + a1 * b1v + a2 * b2v) * INV_SQ3;
        h8 w = *(const h8*)(rp + vv * 32);
        so[0] += (float)w[0] * dd; so[1] += (float)w[1] * dd;
        so[2] += (float)w[2] * dd; so[3] += (float)w[3] * dd;
        so[4] += (float)w[4] * dd; so[5] += (float)w[5] * dd;
        so[6] += (float)w[6] * dd; so[7] += (float)w[7] * dd;
      }
    }
    // W011 @ 2624: [u:16][v:8][w:4], v = vv*4+s
#pragma unroll
    for (int u = 0; u < 16; ++u) {
      const float su = saF[u];
      const _Float16* rp = Wr + 2624 + u * 32 + s * 4;
#pragma unroll
      for (int vv = 0; vv < 2; ++vv) {
        const float q0 = su * (vv ? vbB0 : vbA0);
        const float q1 = su * (vv ? vbB1 : vbA1);
        const float q2 = su * (vv ? vbB2 : vbA2);
        h4 w = *(const h4*)(rp + vv * 16);
        const float w0f = (float)w[0], w1f = (float)w[1], w2f = (float)w[2], w3f = (float)w[3];
        uo[0] += w0f * q0; uo[1]  += w0f * q1; uo[2]  += w0f * q2;
        uo[3] += w1f * q0; uo[4]  += w1f * q1; uo[5]  += w1f * q2;
        uo[6] += w2f * q0; uo[7]  += w2f * q1; uo[8]  += w2f * q2;
        uo[9] += w3f * q0; uo[10] += w3f * q1; uo[11] += w3f * q2;
      }
    }
    // W101 @ 3136: [u:8][v:16][w:4], v = vv*4+s
#pragma unroll
    for (int u = 0; u < 8; ++u) {
      const float a0 = vaF[u * 3], a1 = vaF[u * 3 + 1], a2 = vaF[u * 3 + 2];
      const _Float16* rp = Wr + 3136 + u * 64 + s * 4;
#pragma unroll
      for (int vv = 0; vv < 4; ++vv) {
        const float sbv = (vv == 0) ? sbl0 : (vv == 1) ? sbl1 : (vv == 2) ? sbl2 : sbl3;
        const float q0 = a0 * sbv, q1 = a1 * sbv, q2 = a2 * sbv;
        h4 w = *(const h4*)(rp + vv * 16);
        const float w0f = (float)w[0], w1f = (float)w[1], w2f = (float)w[2], w3f = (float)w[3];
        uo[0] += w0f * q0; uo[1]  += w0f * q1; uo[2]  += w0f * q2;
        uo[3] += w1f * q0; uo[4]  += w1f * q1; uo[5]  += w1f * q2;
        uo[6] += w2f * q0; uo[7]  += w2f * q1; uo[8]  += w2f * q2;
        uo[9] += w3f * q0; uo[10] += w3f * q1; uo[11] += w3f * q2;
      }
    }
#pragma unroll
    for (int w = 0; w < 8; ++w)  oe[w]     += cr * so[w];
#pragma unroll
    for (int w = 0; w < 12; ++w) oe[8 + w] += cr * uo[w];
  }

  // ---- scale, quad butterfly reduce, store ----
#pragma unroll
  for (int w = 0; w < 8; ++w)  oe[w] *= C0_2F;
#pragma unroll
  for (int w = 0; w < 12; ++w) oe[8 + w] *= C1_2_OS3F;
#pragma unroll
  for (int w = 0; w < 20; ++w) {
    oe[w] += __shfl_xor(oe[w], 1, 64);
    oe[w] += __shfl_xor(oe[w], 2, 64);
  }
  if (s == 0) {
    float4* op = (float4*)(out + (size_t)e * 20);
#pragma unroll
    for (int j = 0; j < 5; ++j) {
      float4 o4;
      o4.x = oe[j * 4 + 0]; o4.y = oe[j * 4 + 1];
      o4.z = oe[j * 4 + 2]; o4.w = oe[j * 4 + 3];
      op[j] = o4;
    }
  }
}

// ---------------- host ----------------
extern "C" void kernel_launch(void* const* d_in, const int* in_sizes, int n_in,
                              void* d_out, int out_size, void* d_ws, size_t ws_size,
                              hipStream_t stream) {
  const int*   ei  = (const int*)d_in[0];
  const float* pos = (const float*)d_in[1];
  const float* x   = (const float*)d_in[2];
  const float* lw1 = (const float*)d_in[3];
  const float* lw2 = (const float*)d_in[4];
  const float* rw1 = (const float*)d_in[5];
  const float* rw2 = (const float*)d_in[6];
  float* out = (float*)d_out;
  char*  ws  = (char*)d_ws;

  size_t o = 0;
  _Float16* lut = (_Float16*)(ws + o); o += (size_t)NLUT * NC * 2;
  o = (o + 15) & ~(size_t)15;
  int*   bin_e = (int*)(ws + o);  o += (size_t)NE * 4;
  float* f_e   = (float*)(ws + o); o += (size_t)NE * 4;
  int*   cnt   = (int*)(ws + o);  o += (size_t)GBIN * 4;
  int*   offs  = (int*)(ws + o);  o += (size_t)(GBIN + 1) * 4 + 12;
  int*   woff  = (int*)(ws + o);  o += (size_t)GBIN * 4;
  int*   sorted = (int*)(ws + o); o += (size_t)NE * 4;
  int*   chunk_bin   = (int*)(ws + o); o += (size_t)NCHMAX * 4;
  int*   chunk_start = (int*)(ws + o); o += (size_t)NCHMAX * 4;
  int*   nch = (int*)(ws + o); o += 16;

  // ACT_C on host (runs at capture time, not in the timed graph)
  double ssum = 0.0;
  const double dz = 20.0 / 40000.0;
  for (int i = 0; i <= 40000; ++i) {
    const double z = -10.0 + dz * (double)i;
    const double sil = z / (1.0 + exp(-z));
    const double phi = exp(-0.5 * z * z) / sqrt(2.0 * M_PI);
    ssum += sil * sil * phi;
  }
  const float actc = (float)(1.0 / sqrt(ssum * dz));
  const float k0c  = (float)(1.14136 * exp(2.0));

  hipMemsetAsync(cnt, 0, GBIN * 4, stream);
  k_lut<<<dim3(129, 5), 256, 0, stream>>>(lw1, lw2, rw1, rw2, actc, k0c, lut);
  k_edge<<<(NE + 255) / 256, 256, 0, stream>>>(ei, pos, out, bin_e, f_e, cnt);
  k_scan<<<1, 256, 0, stream>>>(cnt, offs, woff, chunk_bin, chunk_start, nch);
  k_scatter<<<(NE + 255) / 256, 256, 0, stream>>>(bin_e, woff, sorted);
  k_epi<<<NCHMAX, 256, 0, stream>>>(lut, chunk_bin, chunk_start, offs, sorted, f_e,
                                    ei, pos, x, out, nch);
}

// Round 8
// 173.847 us; speedup vs baseline: 1.3697x; 1.3697x over previous
//
#include <hip/hip_runtime.h>
#include <math.h>

#define NE     50000
#define NNODE  10000
#define HDIM   128
#define GBIN   2048
#define NLUT   2049          // GBIN+1 rows
#define NC     4160          // 576 + 3584
#define NC1    576
#define NCHMAX 2834          // 2048 + ceil(50000/64)

typedef _Float16 h4 __attribute__((ext_vector_type(4)));
typedef _Float16 h8 __attribute__((ext_vector_type(8)));

// constants
#define SQ3C        1.7320508075688772f
#define INV_SQ3     0.5773502691896258f
#define C0_1F       0.20412414523193154f   // 1/sqrt(24)
#define C1_1_OS3F   0.20412414523193154f   // sqrt(3/24)/sqrt(3)
#define C0_2F       0.05590169943749474f   // 1/sqrt(320)
#define C1_2_OS3F   0.0625f                // sqrt(3/256)/sqrt(3)
#define INV_SQRT_H  0.08838834764831845f   // 1/sqrt(128)
#define DELTA       (5.0f/2048.0f)
#define INV_DELTA   409.6f
#define STEP_INV    (51.0f/5.0f)

// ---------------- K1: LUT build (fp16 output) ----------------
__global__ __launch_bounds__(256) void k_lut(
    const float* __restrict__ lw1, const float* __restrict__ lw2,
    const float* __restrict__ rw1, const float* __restrict__ rw2,
    const float actc, const float K0C, _Float16* __restrict__ lut) {
  __shared__ float Hs[256][20];
  const int pb = blockIdx.x;
  const int t  = threadIdx.x;
  {
    const int which = t >> 7, hc = t & 127;
    const float* __restrict__ w1 = which ? rw1 : lw1;
#pragma unroll
    for (int m = 0; m < 16; ++m) {
      const int g = pb * 16 + m;
      float h = 0.f;
      if (g <= GBIN) {
        const float d  = (float)g * DELTA;
        const float tt = d * STEP_INV;
        const int   i0 = (int)floorf(tt);
        float z = 0.f;
#pragma unroll
        for (int k = 0; k < 2; ++k) {
          const int ii = i0 + k;
          if (ii >= 1 && ii <= 50) {
            const float diff = tt - (float)ii;
            const float a = diff + 1.f, b = 1.f - diff;
            if (a > 0.f && b > 0.f) {
              const float val = K0C * __expf(-1.f / a - 1.f / b);
              z += val * w1[(ii - 1) * HDIM + hc];
            }
          }
        }
        h = actc * z / (1.f + __expf(-z)) * INV_SQRT_H;
      }
      Hs[t][m] = h;
    }
  }
  __syncthreads();

  const int n0 = blockIdx.y * 1024 + t * 4;
  if (n0 >= NC) return;
  const int isrec = (n0 >= NC1);
  const float* __restrict__ w2 = isrec ? (rw2 + (n0 - NC1)) : (lw2 + n0);
  const int stride = isrec ? 3584 : 576;
  const int hbase  = isrec ? 128 : 0;

  float acc[4][16];
#pragma unroll
  for (int c = 0; c < 4; ++c)
#pragma unroll
    for (int m = 0; m < 16; ++m) acc[c][m] = 0.f;

#pragma unroll 2
  for (int h = 0; h < HDIM; ++h) {
    const float4 wv = *(const float4*)(w2 + (size_t)h * stride);
    const float* hp = &Hs[hbase + h][0];
    const float4 m0 = *(const float4*)(hp);
    const float4 m1 = *(const float4*)(hp + 4);
    const float4 m2 = *(const float4*)(hp + 8);
    const float4 m3 = *(const float4*)(hp + 12);
    float hm[16];
    hm[0]=m0.x; hm[1]=m0.y; hm[2]=m0.z; hm[3]=m0.w;
    hm[4]=m1.x; hm[5]=m1.y; hm[6]=m1.z; hm[7]=m1.w;
    hm[8]=m2.x; hm[9]=m2.y; hm[10]=m2.z; hm[11]=m2.w;
    hm[12]=m3.x; hm[13]=m3.y; hm[14]=m3.z; hm[15]=m3.w;
    float wc[4]; wc[0]=wv.x; wc[1]=wv.y; wc[2]=wv.z; wc[3]=wv.w;
#pragma unroll
    for (int c = 0; c < 4; ++c)
#pragma unroll
      for (int m = 0; m < 16; ++m) acc[c][m] += wc[c] * hm[m];
  }

#pragma unroll
  for (int m = 0; m < 16; ++m) {
    const int g = pb * 16 + m;
    if (g <= GBIN) {
      h4 o;
      o[0] = (_Float16)acc[0][m]; o[1] = (_Float16)acc[1][m];
      o[2] = (_Float16)acc[2][m]; o[3] = (_Float16)acc[3][m];
      *(h4*)(lut + (size_t)g * NC + n0) = o;
    }
  }
}

// ---------------- K2: per-edge bin/frac + histogram; zero inactive outputs ----------------
__global__ void k_edge(const int* __restrict__ ei, const float* __restrict__ pos,
                       float* __restrict__ out, int* __restrict__ bin_e,
                       float* __restrict__ f_e, int* __restrict__ cnt) {
  const int e = blockIdx.x * 256 + threadIdx.x;
  if (e >= NE) return;
  const int rec = ei[e], lig = ei[NE + e];
  const float ax = pos[lig * 3 + 0] - pos[rec * 3 + 0];
  const float ay = pos[lig * 3 + 1] - pos[rec * 3 + 1];
  const float az = pos[lig * 3 + 2] - pos[rec * 3 + 2];
  const float d = sqrtf(ax * ax + ay * ay + az * az);
  if (d > 0.f && d < 5.0f) {
    const float tf = d * INV_DELTA;
    int b = (int)tf;
    if (b > GBIN - 1) b = GBIN - 1;
    bin_e[e] = b;
    f_e[e] = tf - (float)b;
    atomicAdd(&cnt[b], 1);
  } else {
    bin_e[e] = -1;
    float* o = out + (size_t)e * 20;
#pragma unroll
    for (int i2 = 0; i2 < 20; ++i2) o[i2] = 0.f;
  }
}

// ---------------- K3a: scan + chunk-table emission (single block) ----------------
__global__ void k_scan(const int* __restrict__ cnt, int* __restrict__ offs,
                       int* __restrict__ woff, int* __restrict__ chunk_bin,
                       int* __restrict__ chunk_start, int* __restrict__ nch) {
  __shared__ int lds[256];
  const int t = threadIdx.x;
  int loc[8];
  int s = 0;
#pragma unroll
  for (int i = 0; i < 8; ++i) { loc[i] = cnt[t * 8 + i]; s += loc[i]; }
  lds[t] = s;
  __syncthreads();
  for (int o = 1; o < 256; o <<= 1) {
    int v = 0;
    if (t >= o) v = lds[t - o];
    __syncthreads();
    lds[t] += v;
    __syncthreads();
  }
  int run = lds[t] - s;
  int runs[8];
#pragma unroll
  for (int i = 0; i < 8; ++i) {
    runs[i] = run;
    offs[t * 8 + i] = run;
    woff[t * 8 + i] = run;
    run += loc[i];
  }
  if (t == 255) offs[GBIN] = run;

  // second scan: chunk counts (ceil(count/64) per bin)
  int ccnt[8];
  int csum = 0;
#pragma unroll
  for (int i = 0; i < 8; ++i) { ccnt[i] = (loc[i] + 63) >> 6; csum += ccnt[i]; }
  __syncthreads();
  lds[t] = csum;
  __syncthreads();
  for (int o = 1; o < 256; o <<= 1) {
    int v = 0;
    if (t >= o) v = lds[t - o];
    __syncthreads();
    lds[t] += v;
    __syncthreads();
  }
  int crun = lds[t] - csum;
#pragma unroll
  for (int i = 0; i < 8; ++i) {
    for (int c = 0; c < ccnt[i]; ++c) {
      chunk_bin[crun]   = t * 8 + i;
      chunk_start[crun] = runs[i] + c * 64;
      ++crun;
    }
  }
  if (t == 255) nch[0] = lds[255];
}

// ---------------- K3b: counting-sort scatter ----------------
__global__ void k_scatter(const int* __restrict__ bin_e, int* __restrict__ woff,
                          int* __restrict__ sorted) {
  const int e = blockIdx.x * 256 + threadIdx.x;
  if (e >= NE) return;
  const int b = bin_e[e];
  if (b >= 0) {
    const int p = atomicAdd(&woff[b], 1);
    sorted[p] = e;
  }
}

// ---------------- K4: one 64-edge chunk per 128-thread block; 2 edges per lane ----------
// fp32 LDS (staged from fp16 LUT); 4 lanes per edge-pair. Layer 1 output-split per edge
// + quad allgather. Layer 2: merged sweep reading both rows ONCE, feeding FMAs for BOTH
// edges (weight reads shared). Four accumulator sets; lerp at finalize.

// layer-1 for one edge: computes allgathered SAF[16], VAF[24]
#define DO_LAYER1(E, F, SAF, VAF)                                              \
  {                                                                            \
    const int rec_ = ei[(E)], lig_ = ei[NE + (E)];                             \
    const float ax_ = pos[lig_ * 3 + 0] - pos[rec_ * 3 + 0];                   \
    const float ay_ = pos[lig_ * 3 + 1] - pos[rec_ * 3 + 1];                   \
    const float az_ = pos[lig_ * 3 + 2] - pos[rec_ * 3 + 2];                   \
    const float d_ = sqrtf(ax_ * ax_ + ay_ * ay_ + az_ * az_);                 \
    const float in_ = SQ3C / fmaxf(d_, 1e-12f);                                \
    const float sh0_ = ax_ * in_, sh1_ = ay_ * in_, sh2_ = az_ * in_;          \
    float s1_[16], v1_[24];                                                    \
    {                                                                          \
      const float4* xl_ = (const float4*)(x + (size_t)lig_ * 40);              \
      _Pragma("unroll")                                                        \
      for (int j = 0; j < 4; ++j) {                                            \
        float4 v = xl_[j];                                                     \
        s1_[j*4+0] = v.x; s1_[j*4+1] = v.y; s1_[j*4+2] = v.z; s1_[j*4+3] = v.w;\
      }                                                                        \
      _Pragma("unroll")                                                        \
      for (int j = 0; j < 6; ++j) {                                            \
        float4 v = xl_[4 + j];                                                 \
        v1_[j*4+0] = v.x; v1_[j*4+1] = v.y; v1_[j*4+2] = v.z; v1_[j*4+3] = v.w;\
      }                                                                        \
    }                                                                          \
    float vs_[8];                                                              \
    _Pragma("unroll")                                                          \
    for (int u = 0; u < 8; ++u)                                                \
      vs_[u] = (v1_[u*3]*sh0_ + v1_[u*3+1]*sh1_ + v1_[u*3+2]*sh2_) * INV_SQ3;  \
    float A0_[4] = {0.f,0.f,0.f,0.f}, A1_[4] = {0.f,0.f,0.f,0.f};              \
    _Pragma("unroll")                                                          \
    for (int u = 0; u < 16; ++u) {                                             \
      float4 w0 = *(const float4*)(W0 + u * 16 + s * 4);                       \
      float4 w1 = *(const float4*)(W1 + u * 16 + s * 4);                       \
      const float su = s1_[u];                                                 \
      A0_[0] += w0.x*su; A0_[1] += w0.y*su; A0_[2] += w0.z*su; A0_[3] += w0.w*su; \
      A1_[0] += w1.x*su; A1_[1] += w1.y*su; A1_[2] += w1.z*su; A1_[3] += w1.w*su; \
    }                                                                          \
    _Pragma("unroll")                                                          \
    for (int u = 0; u < 8; ++u) {                                              \
      float4 w0 = *(const float4*)(W0 + 448 + u * 16 + s * 4);                 \
      float4 w1 = *(const float4*)(W1 + 448 + u * 16 + s * 4);                 \
      const float su = vs_[u];                                                 \
      A0_[0] += w0.x*su; A0_[1] += w0.y*su; A0_[2] += w0.z*su; A0_[3] += w0.w*su; \
      A1_[0] += w1.x*su; A1_[1] += w1.y*su; A1_[2] += w1.z*su; A1_[3] += w1.w*su; \
    }                                                                          \
    const float sa0_ = C0_1F * (A0_[0] + (F) * (A1_[0] - A0_[0]));             \
    const float sa1_ = C0_1F * (A0_[1] + (F) * (A1_[1] - A0_[1]));             \
    const float sa2_ = C0_1F * (A0_[2] + (F) * (A1_[2] - A0_[2]));             \
    const float sa3_ = C0_1F * (A0_[3] + (F) * (A1_[3] - A0_[3]));             \
    float cA0 = 0.f, cB0 = 0.f, cA1 = 0.f, cB1 = 0.f;                          \
    _Pragma("unroll")                                                          \
    for (int u = 0; u < 16; ++u) {                                             \
      float2 w0 = *(const float2*)(W0 + 256 + u * 8 + s * 2);                  \
      float2 w1 = *(const float2*)(W1 + 256 + u * 8 + s * 2);                  \
      const float su = s1_[u];                                                 \
      cA0 += w0.x * su; cB0 += w0.y * su;                                      \
      cA1 += w1.x * su; cB1 += w1.y * su;                                      \
    }                                                                          \
    float tA0x=0.f,tA0y=0.f,tA0z=0.f, tB0x=0.f,tB0y=0.f,tB0z=0.f;              \
    float tA1x=0.f,tA1y=0.f,tA1z=0.f, tB1x=0.f,tB1y=0.f,tB1z=0.f;              \
    _Pragma("unroll")                                                          \
    for (int u = 0; u < 8; ++u) {                                              \
      float2 w0 = *(const float2*)(W0 + 384 + u * 8 + s * 2);                  \
      float2 w1 = *(const float2*)(W1 + 384 + u * 8 + s * 2);                  \
      const float p0 = v1_[u*3], p1 = v1_[u*3+1], p2 = v1_[u*3+2];             \
      tA0x += w0.x*p0; tA0y += w0.x*p1; tA0z += w0.x*p2;                       \
      tB0x += w0.y*p0; tB0y += w0.y*p1; tB0z += w0.y*p2;                       \
      tA1x += w1.x*p0; tA1y += w1.x*p1; tA1z += w1.x*p2;                       \
      tB1x += w1.y*p0; tB1y += w1.y*p1; tB1z += w1.y*p2;                       \
    }                                                                          \
    const float cA_ = cA0 + (F) * (cA1 - cA0);                                 \
    const float cB_ = cB0 + (F) * (cB1 - cB0);                                 \
    const float vaA0_ = C1_1_OS3F * (cA_*sh0_ + (tA0x + (F)*(tA1x - tA0x)));   \
    const float vaA1_ = C1_1_OS3F * (cA_*sh1_ + (tA0y + (F)*(tA1y - tA0y)));   \
    const float vaA2_ = C1_1_OS3F * (cA_*sh2_ + (tA0z + (F)*(tA1z - tA0z)));   \
    const float vaB0_ = C1_1_OS3F * (cB_*sh0_ + (tB0x + (F)*(tB1x - tB0x)));   \
    const float vaB1_ = C1_1_OS3F * (cB_*sh1_ + (tB0y + (F)*(tB1y - tB0y)));   \
    const float vaB2_ = C1_1_OS3F * (cB_*sh2_ + (tB0z + (F)*(tB1z - tB0z)));   \
    _Pragma("unroll")                                                          \
    for (int k = 0; k < 16; ++k) {                                             \
      const float v = ((k&3)==0) ? sa0_ : ((k&3)==1) ? sa1_ :                  \
                      ((k&3)==2) ? sa2_ : sa3_;                                \
      SAF[k] = __shfl(v, qb + (k >> 2), 64);                                   \
    }                                                                          \
    _Pragma("unroll")                                                          \
    for (int w = 0; w < 8; ++w) {                                              \
      const int src = qb + (w >> 1);                                           \
      const float x0 = (w & 1) ? vaB0_ : vaA0_;                                \
      const float x1 = (w & 1) ? vaB1_ : vaA1_;                                \
      const float x2 = (w & 1) ? vaB2_ : vaA2_;                                \
      VAF[w*3+0] = __shfl(x0, src, 64);                                        \
      VAF[w*3+1] = __shfl(x1, src, 64);                                        \
      VAF[w*3+2] = __shfl(x2, src, 64);                                        \
    }                                                                          \
  }

__global__ __launch_bounds__(128) void k_epi(
    const _Float16* __restrict__ lut, const int* __restrict__ chunk_bin,
    const int* __restrict__ chunk_start, const int* __restrict__ offs,
    const int* __restrict__ sorted, const float* __restrict__ f_e,
    const int* __restrict__ ei, const float* __restrict__ pos,
    const float* __restrict__ x, float* __restrict__ out,
    const int* __restrict__ nch) {
  __shared__ float Wf[2 * NC];          // 33280 B
  const int bid = blockIdx.x;
  if (bid >= nch[0]) return;
  const int b     = chunk_bin[bid];
  const int start = chunk_start[bid];
  const int end0  = offs[b + 1];
  const int end   = (start + 64 < end0) ? (start + 64) : end0;
  const int tid = threadIdx.x;
  {  // stage 2 rows: fp16 -> fp32
    const h8* src = (const h8*)(lut + (size_t)b * NC);
    for (int i = tid; i < 1040; i += 128) {
      h8 w = src[i];
      float4 lo, hi;
      lo.x = (float)w[0]; lo.y = (float)w[1]; lo.z = (float)w[2]; lo.w = (float)w[3];
      hi.x = (float)w[4]; hi.y = (float)w[5]; hi.z = (float)w[6]; hi.w = (float)w[7];
      *(float4*)&Wf[i * 8]     = lo;
      *(float4*)&Wf[i * 8 + 4] = hi;
    }
  }
  __syncthreads();
  const float* __restrict__ W0 = Wf;
  const float* __restrict__ W1 = Wf + NC;
  const int s  = tid & 3;
  const int qb = (tid & 63) & ~3;
  const int slotA = start + (tid >> 2);
  const int slotB = slotA + 32;
  if (slotA >= end) return;
  const int validB = (slotB < end);

  const int eA = sorted[slotA];
  const int eB = sorted[validB ? slotB : slotA];
  const float fA = f_e[eA];
  const float fB = f_e[eB];

  // ---- layer 1 (per edge), allgathered ----
  float saFA[16], vaFA[24], saFB[16], vaFB[24];
  DO_LAYER1(eA, fA, saFA, vaFA);
  DO_LAYER1(eB, fB, saFB, vaFB);

  // ---- rec features: lane's v-subset per edge ----
  float sblA[4], vbA[6], sblB[4], vbB[6];
  {
    const float* xr = x + (size_t)ei[eA] * 40;
#pragma unroll
    for (int j = 0; j < 4; ++j) sblA[j] = xr[j * 4 + s];
#pragma unroll
    for (int k = 0; k < 3; ++k) {
      vbA[k]     = xr[16 + s * 3 + k];
      vbA[3 + k] = xr[16 + (s + 4) * 3 + k];
    }
    const float* xr2 = x + (size_t)ei[eB] * 40;
#pragma unroll
    for (int j = 0; j < 4; ++j) sblB[j] = xr2[j * 4 + s];
#pragma unroll
    for (int k = 0; k < 3; ++k) {
      vbB[k]     = xr2[16 + s * 3 + k];
      vbB[3 + k] = xr2[16 + (s + 4) * 3 + k];
    }
  }

  float oeA[20], oeB[20];

  // ===== s_out: merged sweep, shared weight reads =====
  {
    float s0A[8], s1A[8], s0B[8], s1B[8];
#pragma unroll
    for (int w = 0; w < 8; ++w) { s0A[w]=0.f; s1A[w]=0.f; s0B[w]=0.f; s1B[w]=0.f; }
    // W000 @ 576: [u:16][v:16][w:8], v = vv*4+s
#pragma unroll
    for (int u = 0; u < 16; ++u) {
      const float suA = saFA[u], suB = saFB[u];
      const float* r0 = W0 + 576 + u * 128 + s * 8;
      const float* r1 = W1 + 576 + u * 128 + s * 8;
#pragma unroll
      for (int vv = 0; vv < 4; ++vv) {
        const float pA = suA * sblA[vv];
        const float pB = suB * sblB[vv];
        float4 wa0 = *(const float4*)(r0 + vv * 32);
        float4 wb0 = *(const float4*)(r0 + vv * 32 + 4);
        float4 wa1 = *(const float4*)(r1 + vv * 32);
        float4 wb1 = *(const float4*)(r1 + vv * 32 + 4);
        s0A[0]+=wa0.x*pA; s0A[1]+=wa0.y*pA; s0A[2]+=wa0.z*pA; s0A[3]+=wa0.w*pA;
        s0A[4]+=wb0.x*pA; s0A[5]+=wb0.y*pA; s0A[6]+=wb0.z*pA; s0A[7]+=wb0.w*pA;
        s1A[0]+=wa1.x*pA; s1A[1]+=wa1.y*pA; s1A[2]+=wa1.z*pA; s1A[3]+=wa1.w*pA;
        s1A[4]+=wb1.x*pA; s1A[5]+=wb1.y*pA; s1A[6]+=wb1.z*pA; s1A[7]+=wb1.w*pA;
        s0B[0]+=wa0.x*pB; s0B[1]+=wa0.y*pB; s0B[2]+=wa0.z*pB; s0B[3]+=wa0.w*pB;
        s0B[4]+=wb0.x*pB; s0B[5]+=wb0.y*pB; s0B[6]+=wb0.z*pB; s0B[7]+=wb0.w*pB;
        s1B[0]+=wa1.x*pB; s1B[1]+=wa1.y*pB; s1B[2]+=wa1.z*pB; s1B[3]+=wa1.w*pB;
        s1B[4]+=wb1.x*pB; s1B[5]+=wb1.y*pB; s1B[6]+=wb1.z*pB; s1B[7]+=wb1.w*pB;
      }
    }
    // W110 @ 3648: [u:8][v:8][w:8], v = vv*4+s
#pragma unroll
    for (int u = 0; u < 8; ++u) {
      const float aA0 = vaFA[u*3], aA1 = vaFA[u*3+1], aA2 = vaFA[u*3+2];
      const float aB0 = vaFB[u*3], aB1 = vaFB[u*3+1], aB2 = vaFB[u*3+2];
      const float* r0 = W0 + 3648 + u * 64 + s * 8;
      const float* r1 = W1 + 3648 + u * 64 + s * 8;
#pragma unroll
      for (int vv = 0; vv < 2; ++vv) {
        const float dA = (aA0*vbA[vv*3] + aA1*vbA[vv*3+1] + aA2*vbA[vv*3+2]) * INV_SQ3;
        const float dB = (aB0*vbB[vv*3] + aB1*vbB[vv*3+1] + aB2*vbB[vv*3+2]) * INV_SQ3;
        float4 wa0 = *(const float4*)(r0 + vv * 32);
        float4 wb0 = *(const float4*)(r0 + vv * 32 + 4);
        float4 wa1 = *(const float4*)(r1 + vv * 32);
        float4 wb1 = *(const float4*)(r1 + vv * 32 + 4);
        s0A[0]+=wa0.x*dA; s0A[1]+=wa0.y*dA; s0A[2]+=wa0.z*dA; s0A[3]+=wa0.w*dA;
        s0A[4]+=wb0.x*dA; s0A[5]+=wb0.y*dA; s0A[6]+=wb0.z*dA; s0A[7]+=wb0.w*dA;
        s1A[0]+=wa1.x*dA; s1A[1]+=wa1.y*dA; s1A[2]+=wa1.z*dA; s1A[3]+=wa1.w*dA;
        s1A[4]+=wb1.x*dA; s1A[5]+=wb1.y*dA; s1A[6]+=wb1.z*dA; s1A[7]+=wb1.w*dA;
        s0B[0]+=wa0.x*dB; s0B[1]+=wa0.y*dB; s0B[2]+=wa0.z*dB; s0B[3]+=wa0.w*dB;
        s0B[4]+=wb0.x*dB; s0B[5]+=wb0.y*dB; s0B[6]+=wb0.z*dB; s0B[7]+=wb0.w*dB;
        s1B[0]+=wa1.x*dB; s1B[1]+=wa1.y*dB; s1B[2]+=wa1.z*dB; s1B[3]+=wa1.w*dB;
        s1B[4]+=wb1.x*dB; s1B[5]+=wb1.y*dB; s1B[6]+=wb1.z*dB; s1B[7]+=wb1.w*dB;
      }
    }
#pragma unroll
    for (int w = 0; w < 8; ++w) {
      oeA[w] = C0_2F * (s0A[w] + fA * (s1A[w] - s0A[w]));
      oeB[w] = C0_2F * (s0B[w] + fB * (s1B[w] - s0B[w]));
    }
  }

  // ===== v_out: merged sweep, shared weight reads =====
  {
    float u0A[12], u1A[12], u0B[12], u1B[12];
#pragma unroll
    for (int w = 0; w < 12; ++w) { u0A[w]=0.f; u1A[w]=0.f; u0B[w]=0.f; u1B[w]=0.f; }
    // W011 @ 2624: [u:16][v:8][w:4], v = vv*4+s
#pragma unroll
    for (int u = 0; u < 16; ++u) {
      const float suA = saFA[u], suB = saFB[u];
      const float* r0 = W0 + 2624 + u * 32 + s * 4;
      const float* r1 = W1 + 2624 + u * 32 + s * 4;
#pragma unroll
      for (int vv = 0; vv < 2; ++vv) {
        const float qA0 = suA * vbA[vv*3], qA1 = suA * vbA[vv*3+1], qA2 = suA * vbA[vv*3+2];
        const float qB0 = suB * vbB[vv*3], qB1 = suB * vbB[vv*3+1], qB2 = suB * vbB[vv*3+2];
        float4 w0 = *(const float4*)(r0 + vv * 16);
        float4 w1 = *(const float4*)(r1 + vv * 16);
        u0A[0]+=w0.x*qA0; u0A[1] +=w0.x*qA1; u0A[2] +=w0.x*qA2;
        u0A[3]+=w0.y*qA0; u0A[4] +=w0.y*qA1; u0A[5] +=w0.y*qA2;
        u0A[6]+=w0.z*qA0; u0A[7] +=w0.z*qA1; u0A[8] +=w0.z*qA2;
        u0A[9]+=w0.w*qA0; u0A[10]+=w0.w*qA1; u0A[11]+=w0.w*qA2;
        u1A[0]+=w1.x*qA0; u1A[1] +=w1.x*qA1; u1A[2] +=w1.x*qA2;
        u1A[3]+=w1.y*qA0; u1A[4] +=w1.y*qA1; u1A[5] +=w1.y*qA2;
        u1A[6]+=w1.z*qA0; u1A[7] +=w1.z*qA1; u1A[8] +=w1.z*qA2;
        u1A[9]+=w1.w*qA0; u1A[10]+=w1.w*qA1; u1A[11]+=w1.w*qA2;
        u0B[0]+=w0.x*qB0; u0B[1] +=w0.x*qB1; u0B[2] +=w0.x*qB2;
        u0B[3]+=w0.y*qB0; u0B[4] +=w0.y*qB1; u0B[5] +=w0.y*qB2;
        u0B[6]+=w0.z*qB0; u0B[7] +=w0.z*qB1; u0B[8] +=w0.z*qB2;
        u0B[9]+=w0.w*qB0; u0B[10]+=w0.w*qB1; u0B[11]+=w0.w*qB2;
        u1B[0]+=w1.x*qB0; u1B[1] +=w1.x*qB1; u1B[2] +=w1.x*qB2;
        u1B[3]+=w1.y*qB0; u1B[4] +=w1.y*qB1; u1B[5] +=w1.y*qB2;
        u1B[6]+=w1.z*qB0; u1B[7] +=w1.z*qB1; u1B[8] +=w1.z*qB2;
        u1B[9]+=w1.w*qB0; u1B[10]+=w1.w*qB1; u1B[11]+=w1.w*qB2;
      }
    }
    // W101 @ 3136: [u:8][v:16][w:4], v = vv*4+s
#pragma unroll
    for (int u = 0; u < 8; ++u) {
      const float aA0 = vaFA[u*3], aA1 = vaFA[u*3+1], aA2 = vaFA[u*3+2];
      const float aB0 = vaFB[u*3], aB1 = vaFB[u*3+1], aB2 = vaFB[u*3+2];
      const float* r0 = W0 + 3136 + u * 64 + s * 4;
      const float* r1 = W1 + 3136 + u * 64 + s * 4;
#pragma unroll
      for (int vv = 0; vv < 4; ++vv) {
        const float sA = sblA[vv], sB = sblB[vv];
        const float qA0 = aA0 * sA, qA1 = aA1 * sA, qA2 = aA2 * sA;
        const float qB0 = aB0 * sB, qB1 = aB1 * sB, qB2 = aB2 * sB;
        float4 w0 = *(const float4*)(r0 + vv * 16);
        float4 w1 = *(const float4*)(r1 + vv * 16);
        u0A[0]+=w0.x*qA0; u0A[1] +=w0.x*qA1; u0A[2] +=w0.x*qA2;
        u0A[3]+=w0.y*qA0; u0A[4] +=w0.y*qA1; u0A[5] +=w0.y*qA2;
        u0A[6]+=w0.z*qA0; u0A[7] +=w0.z*qA1; u0A[8] +=w0.z*qA2;
        u0A[9]+=w0.w*qA0; u0A[10]+=w0.w*qA1; u0A[11]+=w0.w*qA2;
        u1A[0]+=w1.x*qA0; u1A[1] +=w1.x*qA1; u1A[2] +=w1.x*qA2;
        u1A[3]+=w1.y*qA0; u1A[4] +=w1.y*qA1; u1A[5] +=w1.y*qA2;
        u1A[6]+=w1.z*qA0; u1A[7] +=w1.z*qA1; u1A[8] +=w1.z*qA2;
        u1A[9]+=w1.w*qA0; u1A[10]+=w1.w*qA1; u1A[11]+=w1.w*qA2;
        u0B[0]+=w0.x*qB0; u0B[1] +=w0.x*qB1; u0B[2] +=w0.x*qB2;
        u0B[3]+=w0.y*qB0; u0B[4] +=w0.y*qB1; u0B[5] +=w0.y*qB2;
        u0B[6]+=w0.z*qB0; u0B[7] +=w0.z*qB1; u0B[8] +=w0.z*qB2;
        u0B[9]+=w0.w*qB0; u0B[10]+=w0.w*qB1; u0B[11]+=w0.w*qB2;
        u1B[0]+=w1.x*qB0; u1B[1] +=w1.x*qB1; u1B[2] +=w1.x*qB2;
        u1B[3]+=w1.y*qB0; u1B[4] +=w1.y*qB1; u1B[5] +=w1.y*qB2;
        u1B[6]+=w1.z*qB0; u1B[7] +=w1.z*qB1; u1B[8] +=w1.z*qB2;
        u1B[9]+=w1.w*qB0; u1B[10]+=w1.w*qB1; u1B[11]+=w1.w*qB2;
      }
    }
#pragma unroll
    for (int w = 0; w < 12; ++w) {
      oeA[8 + w] = C1_2_OS3F * (u0A[w] + fA * (u1A[w] - u0A[w]));
      oeB[8 + w] = C1_2_OS3F * (u0B[w] + fB * (u1B[w] - u0B[w]));
    }
  }

  // ---- quad butterfly reduce + store ----
#pragma unroll
  for (int w = 0; w < 20; ++w) {
    oeA[w] += __shfl_xor(oeA[w], 1, 64);
    oeA[w] += __shfl_xor(oeA[w], 2, 64);
    oeB[w] += __shfl_xor(oeB[w], 1, 64);
    oeB[w] += __shfl_xor(oeB[w], 2, 64);
  }
  if (s == 0) {
    float4* opA = (float4*)(out + (size_t)eA * 20);
#pragma unroll
    for (int j = 0; j < 5; ++j) {
      float4 o4;
      o4.x = oeA[j*4+0]; o4.y = oeA[j*4+1]; o4.z = oeA[j*4+2]; o4.w = oeA[j*4+3];
      opA[j] = o4;
    }
    if (validB) {
      float4* opB = (float4*)(out + (size_t)eB * 20);
#pragma unroll
      for (int j = 0; j < 5; ++j) {
        float4 o4;
        o4.x = oeB[j*4+0]; o4.y = oeB[j*4+1]; o4.z = oeB[j*4+2]; o4.w = oeB[j*4+3];
        opB[j] = o4;
      }
    }
  }
}

// ---------------- host ----------------
extern "C" void kernel_launch(void* const* d_in, const int* in_sizes, int n_in,
                              void* d_out, int out_size, void* d_ws, size_t ws_size,
                              hipStream_t stream) {
  const int*   ei  = (const int*)d_in[0];
  const float* pos = (const float*)d_in[1];
  const float* x   = (const float*)d_in[2];
  const float* lw1 = (const float*)d_in[3];
  const float* lw2 = (const float*)d_in[4];
  const float* rw1 = (const float*)d_in[5];
  const float* rw2 = (const float*)d_in[6];
  float* out = (float*)d_out;
  char*  ws  = (char*)d_ws;

  size_t o = 0;
  _Float16* lut = (_Float16*)(ws + o); o += (size_t)NLUT * NC * 2;
  o = (o + 15) & ~(size_t)15;
  int*   bin_e = (int*)(ws + o);  o += (size_t)NE * 4;
  float* f_e   = (float*)(ws + o); o += (size_t)NE * 4;
  int*   cnt   = (int*)(ws + o);  o += (size_t)GBIN * 4;
  int*   offs  = (int*)(ws + o);  o += (size_t)(GBIN + 1) * 4 + 12;
  int*   woff  = (int*)(ws + o);  o += (size_t)GBIN * 4;
  int*   sorted = (int*)(ws + o); o += (size_t)NE * 4;
  int*   chunk_bin   = (int*)(ws + o); o += (size_t)NCHMAX * 4;
  int*   chunk_start = (int*)(ws + o); o += (size_t)NCHMAX * 4;
  int*   nch = (int*)(ws + o); o += 16;

  // ACT_C on host (runs at capture time, not in the timed graph)
  double ssum = 0.0;
  const double dz = 20.0 / 40000.0;
  for (int i = 0; i <= 40000; ++i) {
    const double z = -10.0 + dz * (double)i;
    const double sil = z / (1.0 + exp(-z));
    const double phi = exp(-0.5 * z * z) / sqrt(2.0 * M_PI);
    ssum += sil * sil * phi;
  }
  const float actc = (float)(1.0 / sqrt(ssum * dz));
  const float k0c  = (float)(1.14136 * exp(2.0));

  hipMemsetAsync(cnt, 0, GBIN * 4, stream);
  k_lut<<<dim3(129, 5), 256, 0, stream>>>(lw1, lw2, rw1, rw2, actc, k0c, lut);
  k_edge<<<(NE + 255) / 256, 256, 0, stream>>>(ei, pos, out, bin_e, f_e, cnt);
  k_scan<<<1, 256, 0, stream>>>(cnt, offs, woff, chunk_bin, chunk_start, nch);
  k_scatter<<<(NE + 255) / 256, 256, 0, stream>>>(bin_e, woff, sorted);
  k_epi<<<NCHMAX, 128, 0, stream>>>(lut, chunk_bin, chunk_start, offs, sorted, f_e,
                                    ei, pos, x, out, nch);
}

// Round 9
// 154.458 us; speedup vs baseline: 1.5416x; 1.1255x over previous
//
#include <hip/hip_runtime.h>
#include <math.h>

#define NE     50000
#define NNODE  10000
#define HDIM   128
#define GBIN   2048
#define NLUT   2049          // GBIN+1 rows
#define NC     4160          // 576 + 3584
#define NC1    576
#define NCHMAX 3611          // 2048 + ceil(50000/32)
#define MPAD   2064          // 129*16 padded grid rows

typedef _Float16 h2 __attribute__((ext_vector_type(2)));
typedef _Float16 h8 __attribute__((ext_vector_type(8)));
typedef float f32x4 __attribute__((ext_vector_type(4)));

// constants
#define SQ3C        1.7320508075688772f
#define INV_SQ3     0.5773502691896258f
#define C0_1F       0.20412414523193154f   // 1/sqrt(24)
#define C1_1_OS3F   0.20412414523193154f   // sqrt(3/24)/sqrt(3)
#define C0_2F       0.05590169943749474f   // 1/sqrt(320)
#define C1_2_OS3F   0.0625f                // sqrt(3/256)/sqrt(3)
#define INV_SQRT_H  0.08838834764831845f   // 1/sqrt(128)
#define DELTA       (5.0f/2048.0f)
#define INV_DELTA   409.6f
#define STEP_INV    (51.0f/5.0f)

// ---------------- K1a: H activations (fp16), actc/sqrt(H) folded ----------------
// grid (2064, 2) x 128 threads; blockIdx.y selects lig/rec.
__global__ __launch_bounds__(128) void k_hprep(
    const float* __restrict__ lw1, const float* __restrict__ rw1,
    const float actc, const float K0C,
    _Float16* __restrict__ Hl, _Float16* __restrict__ Hr) {
  const int g  = blockIdx.x;
  const int which = blockIdx.y;
  const int hc = threadIdx.x;
  const float* __restrict__ w1 = which ? rw1 : lw1;
  float h = 0.f;
  if (g <= GBIN) {
    const float tt = (float)g * DELTA * STEP_INV;
    const int i0 = (int)floorf(tt);
    float z = 0.f;
#pragma unroll
    for (int k = 0; k < 2; ++k) {
      const int ii = i0 + k;
      if (ii >= 1 && ii <= 50) {
        const float diff = tt - (float)ii;
        const float a = diff + 1.f, b = 1.f - diff;
        if (a > 0.f && b > 0.f) {
          const float val = K0C * __expf(-1.f / a - 1.f / b);
          z += val * w1[(ii - 1) * HDIM + hc];
        }
      }
    }
    h = actc * z / (1.f + __expf(-z)) * INV_SQRT_H;
  }
  _Float16* __restrict__ H = which ? Hr : Hl;
  H[(size_t)g * HDIM + hc] = (_Float16)h;
}

// ---------------- K1b: W2 -> W2T[n][k] fp16 ----------------
// gid = k2*4160 + n (coalesced reads along n); writes h2 pair (k=2*k2, 2*k2+1).
__global__ __launch_bounds__(256) void k_w2t(
    const float* __restrict__ lw2, const float* __restrict__ rw2,
    _Float16* __restrict__ w2t) {
  const int gid = blockIdx.x * 256 + threadIdx.x;
  if (gid >= 64 * NC) return;
  const int k2 = gid / NC;
  const int n  = gid - k2 * NC;
  float a, b;
  if (n < NC1) {
    a = lw2[(size_t)(2 * k2) * NC1 + n];
    b = lw2[(size_t)(2 * k2 + 1) * NC1 + n];
  } else {
    const int m = n - NC1;
    a = rw2[(size_t)(2 * k2) * 3584 + m];
    b = rw2[(size_t)(2 * k2 + 1) * 3584 + m];
  }
  h2 p; p[0] = (_Float16)a; p[1] = (_Float16)b;
  *(h2*)(w2t + (size_t)n * HDIM + 2 * k2) = p;
}

// ---------------- K1c: LUT build via MFMA GEMM ----------------
// D[2049x4160] = H[2049x128] x W2[128x4160]; one 16x16 tile per wave.
// A from H [M][K] row-major; B from W2T [N][K] (B^T-input convention).
__global__ __launch_bounds__(256) void k_lutm(
    const _Float16* __restrict__ Hl, const _Float16* __restrict__ Hr,
    const _Float16* __restrict__ w2t, _Float16* __restrict__ lut) {
  const int tid = threadIdx.x;
  const int nt = blockIdx.y * 4 + (tid >> 6);   // 0..259
  const int mt = blockIdx.x;                     // 0..128
  const int l  = tid & 63;
  const int rc = l & 15;
  const int kg = (l >> 4) * 8;
  const _Float16* __restrict__ Ap =
      ((nt < 36) ? Hl : Hr) + (size_t)(mt * 16 + rc) * HDIM + kg;
  const _Float16* __restrict__ Bp = w2t + (size_t)(nt * 16 + rc) * HDIM + kg;
  f32x4 acc = {0.f, 0.f, 0.f, 0.f};
#pragma unroll
  for (int kc = 0; kc < 4; ++kc) {
    h8 a = *(const h8*)(Ap + kc * 32);
    h8 b = *(const h8*)(Bp + kc * 32);
    acc = __builtin_amdgcn_mfma_f32_16x16x32_f16(a, b, acc, 0, 0, 0);
  }
#pragma unroll
  for (int r = 0; r < 4; ++r) {
    const int g = mt * 16 + (l >> 4) * 4 + r;
    if (g <= GBIN) lut[(size_t)g * NC + nt * 16 + rc] = (_Float16)acc[r];
  }
}

// ---------------- K2: per-edge bin/frac + histogram; zero inactive outputs ----------------
__global__ void k_edge(const int* __restrict__ ei, const float* __restrict__ pos,
                       float* __restrict__ out, int* __restrict__ bin_e,
                       float* __restrict__ f_e, int* __restrict__ cnt) {
  const int e = blockIdx.x * 256 + threadIdx.x;
  if (e >= NE) return;
  const int rec = ei[e], lig = ei[NE + e];
  const float ax = pos[lig * 3 + 0] - pos[rec * 3 + 0];
  const float ay = pos[lig * 3 + 1] - pos[rec * 3 + 1];
  const float az = pos[lig * 3 + 2] - pos[rec * 3 + 2];
  const float d = sqrtf(ax * ax + ay * ay + az * az);
  if (d > 0.f && d < 5.0f) {
    const float tf = d * INV_DELTA;
    int b = (int)tf;
    if (b > GBIN - 1) b = GBIN - 1;
    bin_e[e] = b;
    f_e[e] = tf - (float)b;
    atomicAdd(&cnt[b], 1);
  } else {
    bin_e[e] = -1;
    float* o = out + (size_t)e * 20;
#pragma unroll
    for (int i2 = 0; i2 < 20; ++i2) o[i2] = 0.f;
  }
}

// ---------------- K3a: scan + chunk-table emission (single block) ----------------
__global__ void k_scan(const int* __restrict__ cnt, int* __restrict__ offs,
                       int* __restrict__ woff, int* __restrict__ chunk_bin,
                       int* __restrict__ chunk_start, int* __restrict__ nch) {
  __shared__ int lds[256];
  const int t = threadIdx.x;
  int loc[8];
  int s = 0;
#pragma unroll
  for (int i = 0; i < 8; ++i) { loc[i] = cnt[t * 8 + i]; s += loc[i]; }
  lds[t] = s;
  __syncthreads();
  for (int o = 1; o < 256; o <<= 1) {
    int v = 0;
    if (t >= o) v = lds[t - o];
    __syncthreads();
    lds[t] += v;
    __syncthreads();
  }
  int run = lds[t] - s;
  int runs[8];
#pragma unroll
  for (int i = 0; i < 8; ++i) {
    runs[i] = run;
    offs[t * 8 + i] = run;
    woff[t * 8 + i] = run;
    run += loc[i];
  }
  if (t == 255) offs[GBIN] = run;

  // second scan: chunk counts (ceil(count/32) per bin)
  int ccnt[8];
  int csum = 0;
#pragma unroll
  for (int i = 0; i < 8; ++i) { ccnt[i] = (loc[i] + 31) >> 5; csum += ccnt[i]; }
  __syncthreads();
  lds[t] = csum;
  __syncthreads();
  for (int o = 1; o < 256; o <<= 1) {
    int v = 0;
    if (t >= o) v = lds[t - o];
    __syncthreads();
    lds[t] += v;
    __syncthreads();
  }
  int crun = lds[t] - csum;
#pragma unroll
  for (int i = 0; i < 8; ++i) {
    for (int c = 0; c < ccnt[i]; ++c) {
      chunk_bin[crun]   = t * 8 + i;
      chunk_start[crun] = runs[i] + c * 32;
      ++crun;
    }
  }
  if (t == 255) nch[0] = lds[255];
}

// ---------------- K3b: counting-sort scatter ----------------
__global__ void k_scatter(const int* __restrict__ bin_e, int* __restrict__ woff,
                          int* __restrict__ sorted) {
  const int e = blockIdx.x * 256 + threadIdx.x;
  if (e >= NE) return;
  const int b = bin_e[e];
  if (b >= 0) {
    const int p = atomicAdd(&woff[b], 1);
    sorted[p] = e;
  }
}

// ---------------- K4: epilogue: one 32-edge chunk per 128-thread block ----------------
// (proven R6 config: fp16 LUT -> fp32 LDS staged once per chunk; 4 lanes/edge;
// layer 1 output-split + quad allgather; layer 2 v-split; two row passes.)
__global__ __launch_bounds__(128) void k_epi(
    const _Float16* __restrict__ lut, const int* __restrict__ chunk_bin,
    const int* __restrict__ chunk_start, const int* __restrict__ offs,
    const int* __restrict__ sorted, const float* __restrict__ f_e,
    const int* __restrict__ ei, const float* __restrict__ pos,
    const float* __restrict__ x, float* __restrict__ out,
    const int* __restrict__ nch) {
  __shared__ float Wf[2 * NC];          // 33280 B
  const int bid = blockIdx.x;
  if (bid >= nch[0]) return;
  const int b     = chunk_bin[bid];
  const int start = chunk_start[bid];
  const int end0  = offs[b + 1];
  const int end   = (start + 32 < end0) ? (start + 32) : end0;
  const int tid = threadIdx.x;
  {  // stage 2 rows: 1040 h8 (16B) loads, cvt to fp32, 2x ds_write_b128 each
    const h8* src = (const h8*)(lut + (size_t)b * NC);
    for (int i = tid; i < 1040; i += 128) {
      h8 w = src[i];
      float4 lo, hi;
      lo.x = (float)w[0]; lo.y = (float)w[1]; lo.z = (float)w[2]; lo.w = (float)w[3];
      hi.x = (float)w[4]; hi.y = (float)w[5]; hi.z = (float)w[6]; hi.w = (float)w[7];
      *(float4*)&Wf[i * 8]     = lo;
      *(float4*)&Wf[i * 8 + 4] = hi;
    }
  }
  __syncthreads();
  const float* __restrict__ W0 = Wf;
  const float* __restrict__ W1 = Wf + NC;
  const int s  = tid & 3;
  const int qb = (tid & 63) & ~3;
  const int slot = start + (tid >> 2);
  if (slot >= end) return;

  const int e = sorted[slot];
  const float f = f_e[e];
  const int rec = ei[e], lig = ei[NE + e];
  const float ax = pos[lig * 3 + 0] - pos[rec * 3 + 0];
  const float ay = pos[lig * 3 + 1] - pos[rec * 3 + 1];
  const float az = pos[lig * 3 + 2] - pos[rec * 3 + 2];
  const float d = sqrtf(ax * ax + ay * ay + az * az);
  const float inv = SQ3C / fmaxf(d, 1e-12f);
  const float sh0 = ax * inv, sh1 = ay * inv, sh2 = az * inv;

  // ---- lig features ----
  float s1[16], v1[24];
  {
    const float4* xl = (const float4*)(x + (size_t)lig * 40);
#pragma unroll
    for (int j = 0; j < 4; ++j) {
      float4 v = xl[j];
      s1[j * 4 + 0] = v.x; s1[j * 4 + 1] = v.y; s1[j * 4 + 2] = v.z; s1[j * 4 + 3] = v.w;
    }
#pragma unroll
    for (int j = 0; j < 6; ++j) {
      float4 v = xl[4 + j];
      v1[j * 4 + 0] = v.x; v1[j * 4 + 1] = v.y; v1[j * 4 + 2] = v.z; v1[j * 4 + 3] = v.w;
    }
  }
  float vs[8];
#pragma unroll
  for (int u = 0; u < 8; ++u)
    vs[u] = (v1[u * 3] * sh0 + v1[u * 3 + 1] * sh1 + v1[u * 3 + 2] * sh2) * INV_SQ3;

  // ---- layer 1: sa (lane owns w = 4s..4s+3) ----
  float A0[4] = {0.f, 0.f, 0.f, 0.f}, A1[4] = {0.f, 0.f, 0.f, 0.f};
#pragma unroll
  for (int u = 0; u < 16; ++u) {   // W000 @ 0: [u:16][w:16]
    float4 w0 = *(const float4*)(W0 + u * 16 + s * 4);
    float4 w1 = *(const float4*)(W1 + u * 16 + s * 4);
    const float su = s1[u];
    A0[0] += w0.x * su; A0[1] += w0.y * su; A0[2] += w0.z * su; A0[3] += w0.w * su;
    A1[0] += w1.x * su; A1[1] += w1.y * su; A1[2] += w1.z * su; A1[3] += w1.w * su;
  }
#pragma unroll
  for (int u = 0; u < 8; ++u) {    // W110 @ 448: [u:8][w:16]
    float4 w0 = *(const float4*)(W0 + 448 + u * 16 + s * 4);
    float4 w1 = *(const float4*)(W1 + 448 + u * 16 + s * 4);
    const float su = vs[u];
    A0[0] += w0.x * su; A0[1] += w0.y * su; A0[2] += w0.z * su; A0[3] += w0.w * su;
    A1[0] += w1.x * su; A1[1] += w1.y * su; A1[2] += w1.z * su; A1[3] += w1.w * su;
  }
  const float sa0 = C0_1F * (A0[0] + f * (A1[0] - A0[0]));
  const float sa1 = C0_1F * (A0[1] + f * (A1[1] - A0[1]));
  const float sa2 = C0_1F * (A0[2] + f * (A1[2] - A0[2]));
  const float sa3 = C0_1F * (A0[3] + f * (A1[3] - A0[3]));

  // ---- layer 1: va (lane owns w = 2s, 2s+1) ----
  float vaA0, vaA1, vaA2, vaB0, vaB1, vaB2;
  {
    float cA0 = 0.f, cB0 = 0.f, cA1 = 0.f, cB1 = 0.f;
#pragma unroll
    for (int u = 0; u < 16; ++u) {  // W011 @ 256: [u:16][w:8]
      float2 w0 = *(const float2*)(W0 + 256 + u * 8 + s * 2);
      float2 w1 = *(const float2*)(W1 + 256 + u * 8 + s * 2);
      const float su = s1[u];
      cA0 += w0.x * su; cB0 += w0.y * su;
      cA1 += w1.x * su; cB1 += w1.y * su;
    }
    float tA0x=0.f,tA0y=0.f,tA0z=0.f, tB0x=0.f,tB0y=0.f,tB0z=0.f;
    float tA1x=0.f,tA1y=0.f,tA1z=0.f, tB1x=0.f,tB1y=0.f,tB1z=0.f;
#pragma unroll
    for (int u = 0; u < 8; ++u) {   // W101 @ 384: [u:8][w:8]
      float2 w0 = *(const float2*)(W0 + 384 + u * 8 + s * 2);
      float2 w1 = *(const float2*)(W1 + 384 + u * 8 + s * 2);
      const float p0 = v1[u * 3], p1 = v1[u * 3 + 1], p2 = v1[u * 3 + 2];
      tA0x += w0.x * p0; tA0y += w0.x * p1; tA0z += w0.x * p2;
      tB0x += w0.y * p0; tB0y += w0.y * p1; tB0z += w0.y * p2;
      tA1x += w1.x * p0; tA1y += w1.x * p1; tA1z += w1.x * p2;
      tB1x += w1.y * p0; tB1y += w1.y * p1; tB1z += w1.y * p2;
    }
    const float cA = cA0 + f * (cA1 - cA0);
    const float cB = cB0 + f * (cB1 - cB0);
    vaA0 = C1_1_OS3F * (cA * sh0 + (tA0x + f * (tA1x - tA0x)));
    vaA1 = C1_1_OS3F * (cA * sh1 + (tA0y + f * (tA1y - tA0y)));
    vaA2 = C1_1_OS3F * (cA * sh2 + (tA0z + f * (tA1z - tA0z)));
    vaB0 = C1_1_OS3F * (cB * sh0 + (tB0x + f * (tB1x - tB0x)));
    vaB1 = C1_1_OS3F * (cB * sh1 + (tB0y + f * (tB1y - tB0y)));
    vaB2 = C1_1_OS3F * (cB * sh2 + (tB0z + f * (tB1z - tB0z)));
  }

  // ---- quad allgather ----
  float saF[16];
#pragma unroll
  for (int k = 0; k < 16; ++k) {
    const float v = ((k & 3) == 0) ? sa0 : ((k & 3) == 1) ? sa1 : ((k & 3) == 2) ? sa2 : sa3;
    saF[k] = __shfl(v, qb + (k >> 2), 64);
  }
  float vaF[24];
#pragma unroll
  for (int w = 0; w < 8; ++w) {
    const int src = qb + (w >> 1);
    const float x0 = (w & 1) ? vaB0 : vaA0;
    const float x1 = (w & 1) ? vaB1 : vaA1;
    const float x2 = (w & 1) ? vaB2 : vaA2;
    vaF[w * 3 + 0] = __shfl(x0, src, 64);
    vaF[w * 3 + 1] = __shfl(x1, src, 64);
    vaF[w * 3 + 2] = __shfl(x2, src, 64);
  }

  // ---- rec features: lane's v-subset ----
  const float* xr = x + (size_t)rec * 40;
  const float sbl0 = xr[s],      sbl1 = xr[4 + s];
  const float sbl2 = xr[8 + s],  sbl3 = xr[12 + s];
  const float vbA0 = xr[16 + s * 3 + 0], vbA1 = xr[16 + s * 3 + 1], vbA2 = xr[16 + s * 3 + 2];
  const float vbB0 = xr[16 + (s + 4) * 3 + 0], vbB1 = xr[16 + (s + 4) * 3 + 1], vbB2 = xr[16 + (s + 4) * 3 + 2];

  // ---- layer 2: two row passes ----
  float oe[20];
#pragma unroll
  for (int w = 0; w < 20; ++w) oe[w] = 0.f;
#pragma unroll
  for (int r = 0; r < 2; ++r) {
    const float* __restrict__ Wr = r ? W1 : W0;
    const float cr = r ? f : (1.f - f);
    float so[8];
    float uo[12];
#pragma unroll
    for (int w = 0; w < 8; ++w) so[w] = 0.f;
#pragma unroll
    for (int w = 0; w < 12; ++w) uo[w] = 0.f;

    // W000 @ 576: [u:16][v:16][w:8], v = vv*4+s
#pragma unroll
    for (int u = 0; u < 16; ++u) {
      const float su = saF[u];
      const float* rp = Wr + 576 + u * 128 + s * 8;
#pragma unroll
      for (int vv = 0; vv < 4; ++vv) {
        const float p = su * ((vv == 0) ? sbl0 : (vv == 1) ? sbl1 : (vv == 2) ? sbl2 : sbl3);
        float4 wa = *(const float4*)(rp + vv * 32);
        float4 wb = *(const float4*)(rp + vv * 32 + 4);
        so[0] += wa.x * p; so[1] += wa.y * p; so[2] += wa.z * p; so[3] += wa.w * p;
        so[4] += wb.x * p; so[5] += wb.y * p; so[6] += wb.z * p; so[7] += wb.w * p;
      }
    }
    // W110 @ 3648: [u:8][v:8][w:8], v = vv*4+s
#pragma unroll
    for (int u = 0; u < 8; ++u) {
      const float a0 = vaF[u * 3], a1 = vaF[u * 3 + 1], a2 = vaF[u * 3 + 2];
      const float* rp = Wr + 3648 + u * 64 + s * 8;
#pragma unroll
      for (int vv = 0; vv < 2; ++vv) {
        const float b0v = vv ? vbB0 : vbA0;
        const float b1v = vv ? vbB1 : vbA1;
        const float b2v = vv ? vbB2 : vbA2;
        const float dd = (a0 * b0v + a1 * b1v + a2 * b2v) * INV_SQ3;
        float4 wa = *(const float4*)(rp + vv * 32);
        float4 wb = *(const float4*)(rp + vv * 32 + 4);
        so[0] += wa.x * dd; so[1] += wa.y * dd; so[2] += wa.z * dd; so[3] += wa.w * dd;
        so[4] += wb.x * dd; so[5] += wb.y * dd; so[6] += wb.z * dd; so[7] += wb.w * dd;
      }
    }
    // W011 @ 2624: [u:16][v:8][w:4], v = vv*4+s
#pragma unroll
    for (int u = 0; u < 16; ++u) {
      const float su = saF[u];
      const float* rp = Wr + 2624 + u * 32 + s * 4;
#pragma unroll
      for (int vv = 0; vv < 2; ++vv) {
        const float q0 = su * (vv ? vbB0 : vbA0);
        const float q1 = su * (vv ? vbB1 : vbA1);
        const float q2 = su * (vv ? vbB2 : vbA2);
        float4 w = *(const float4*)(rp + vv * 16);
        uo[0] += w.x * q0; uo[1]  += w.x * q1; uo[2]  += w.x * q2;
        uo[3] += w.y * q0; uo[4]  += w.y * q1; uo[5]  += w.y * q2;
        uo[6] += w.z * q0; uo[7]  += w.z * q1; uo[8]  += w.z * q2;
        uo[9] += w.w * q0; uo[10] += w.w * q1; uo[11] += w.w * q2;
      }
    }
    // W101 @ 3136: [u:8][v:16][w:4], v = vv*4+s
#pragma unroll
    for (int u = 0; u < 8; ++u) {
      const float a0 = vaF[u * 3], a1 = vaF[u * 3 + 1], a2 = vaF[u * 3 + 2];
      const float* rp = Wr + 3136 + u * 64 + s * 4;
#pragma unroll
      for (int vv = 0; vv < 4; ++vv) {
        const float sbv = (vv == 0) ? sbl0 : (vv == 1) ? sbl1 : (vv == 2) ? sbl2 : sbl3;
        const float q0 = a0 * sbv, q1 = a1 * sbv, q2 = a2 * sbv;
        float4 w = *(const float4*)(rp + vv * 16);
        uo[0] += w.x * q0; uo[1]  += w.x * q1; uo[2]  += w.x * q2;
        uo[3] += w.y * q0; uo[4]  += w.y * q1; uo[5]  += w.y * q2;
        uo[6] += w.z * q0; uo[7]  += w.z * q1; uo[8]  += w.z * q2;
        uo[9] += w.w * q0; uo[10] += w.w * q1; uo[11] += w.w * q2;
      }
    }
#pragma unroll
    for (int w = 0; w < 8; ++w)  oe[w]     += cr * so[w];
#pragma unroll
    for (int w = 0; w < 12; ++w) oe[8 + w] += cr * uo[w];
  }

  // ---- scale, quad butterfly reduce, store ----
#pragma unroll
  for (int w = 0; w < 8; ++w)  oe[w] *= C0_2F;
#pragma unroll
  for (int w = 0; w < 12; ++w) oe[8 + w] *= C1_2_OS3F;
#pragma unroll
  for (int w = 0; w < 20; ++w) {
    oe[w] += __shfl_xor(oe[w], 1, 64);
    oe[w] += __shfl_xor(oe[w], 2, 64);
  }
  if (s == 0) {
    float4* op = (float4*)(out + (size_t)e * 20);
#pragma unroll
    for (int j = 0; j < 5; ++j) {
      float4 o4;
      o4.x = oe[j * 4 + 0]; o4.y = oe[j * 4 + 1];
      o4.z = oe[j * 4 + 2]; o4.w = oe[j * 4 + 3];
      op[j] = o4;
    }
  }
}

// ---------------- host ----------------
extern "C" void kernel_launch(void* const* d_in, const int* in_sizes, int n_in,
                              void* d_out, int out_size, void* d_ws, size_t ws_size,
                              hipStream_t stream) {
  const int*   ei  = (const int*)d_in[0];
  const float* pos = (const float*)d_in[1];
  const float* x   = (const float*)d_in[2];
  const float* lw1 = (const float*)d_in[3];
  const float* lw2 = (const float*)d_in[4];
  const float* rw1 = (const float*)d_in[5];
  const float* rw2 = (const float*)d_in[6];
  float* out = (float*)d_out;
  char*  ws  = (char*)d_ws;

  size_t o = 0;
  _Float16* lut = (_Float16*)(ws + o); o += (size_t)NLUT * NC * 2;
  o = (o + 15) & ~(size_t)15;
  _Float16* Hl  = (_Float16*)(ws + o); o += (size_t)MPAD * HDIM * 2;
  _Float16* Hr  = (_Float16*)(ws + o); o += (size_t)MPAD * HDIM * 2;
  _Float16* w2t = (_Float16*)(ws + o); o += (size_t)NC * HDIM * 2;
  o = (o + 15) & ~(size_t)15;
  int*   bin_e = (int*)(ws + o);  o += (size_t)NE * 4;
  float* f_e   = (float*)(ws + o); o += (size_t)NE * 4;
  int*   cnt   = (int*)(ws + o);  o += (size_t)GBIN * 4;
  int*   offs  = (int*)(ws + o);  o += (size_t)(GBIN + 1) * 4 + 12;
  int*   woff  = (int*)(ws + o);  o += (size_t)GBIN * 4;
  int*   sorted = (int*)(ws + o); o += (size_t)NE * 4;
  int*   chunk_bin   = (int*)(ws + o); o += (size_t)NCHMAX * 4;
  int*   chunk_start = (int*)(ws + o); o += (size_t)NCHMAX * 4;
  int*   nch = (int*)(ws + o); o += 16;

  // ACT_C on host (runs at capture time, not in the timed graph)
  double ssum = 0.0;
  const double dz = 20.0 / 40000.0;
  for (int i = 0; i <= 40000; ++i) {
    const double z = -10.0 + dz * (double)i;
    const double sil = z / (1.0 + exp(-z));
    const double phi = exp(-0.5 * z * z) / sqrt(2.0 * M_PI);
    ssum += sil * sil * phi;
  }
  const float actc = (float)(1.0 / sqrt(ssum * dz));
  const float k0c  = (float)(1.14136 * exp(2.0));

  hipMemsetAsync(cnt, 0, GBIN * 4, stream);
  k_hprep<<<dim3(MPAD, 2), 128, 0, stream>>>(lw1, rw1, actc, k0c, Hl, Hr);
  k_w2t<<<(64 * NC + 255) / 256, 256, 0, stream>>>(lw2, rw2, w2t);
  k_lutm<<<dim3(129, 65), 256, 0, stream>>>(Hl, Hr, w2t, lut);
  k_edge<<<(NE + 255) / 256, 256, 0, stream>>>(ei, pos, out, bin_e, f_e, cnt);
  k_scan<<<1, 256, 0, stream>>>(cnt, offs, woff, chunk_bin, chunk_start, nch);
  k_scatter<<<(NE + 255) / 256, 256, 0, stream>>>(bin_e, woff, sorted);
  k_epi<<<NCHMAX, 128, 0, stream>>>(lut, chunk_bin, chunk_start, offs, sorted, f_e,
                                    ei, pos, x, out, nch);
}

// Round 12
// 111.489 us; speedup vs baseline: 2.1358x; 1.3854x over previous
//
#include <hip/hip_runtime.h>
#include <math.h>

#define NE     50000
#define NNODE  10000
#define HDIM   128
#define GBIN   2048
#define NLUT   2049          // GBIN+1 rows
#define NC     4160          // 576 + 3584
#define NC1    576
#define NCHMAX 3611          // 2048 + ceil(50000/32)
#define MPAD   2064          // 129*16 padded grid rows

typedef _Float16 h2 __attribute__((ext_vector_type(2)));
typedef _Float16 h8 __attribute__((ext_vector_type(8)));
typedef float f32x4 __attribute__((ext_vector_type(4)));

// fp16 types for k_epi dot2 path
typedef __fp16 hp2 __attribute__((ext_vector_type(2)));
typedef __fp16 hp4 __attribute__((ext_vector_type(4)));
typedef __fp16 hp8 __attribute__((ext_vector_type(8)));

static __device__ __forceinline__ float fdot2f(hp2 p, hp2 q, float acc) {
  return __builtin_amdgcn_fdot2(p, q, acc, false);
}
static __device__ __forceinline__ hp2 pk2(float a, float b) {
  hp2 r = __builtin_amdgcn_cvt_pkrtz(a, b);
  return r;
}
static __device__ __forceinline__ hp2 mkh2(__fp16 a, __fp16 b) {
  hp2 o; o[0] = a; o[1] = b;
  return o;
}

// constants
#define SQ3C        1.7320508075688772f
#define INV_SQ3     0.5773502691896258f
#define C0_1F       0.20412414523193154f   // 1/sqrt(24)
#define C1_1_OS3F   0.20412414523193154f   // sqrt(3/24)/sqrt(3)
#define C0_2F       0.05590169943749474f   // 1/sqrt(320)
#define C1_2_OS3F   0.0625f                // sqrt(3/256)/sqrt(3)
#define INV_SQRT_H  0.08838834764831845f   // 1/sqrt(128)
#define DELTA       (5.0f/2048.0f)
#define INV_DELTA   409.6f
#define STEP_INV    (51.0f/5.0f)

// ---------------- K1a: H activations (fp16), actc/sqrt(H) folded ----------------
__global__ __launch_bounds__(128) void k_hprep(
    const float* __restrict__ lw1, const float* __restrict__ rw1,
    const float actc, const float K0C,
    _Float16* __restrict__ Hl, _Float16* __restrict__ Hr) {
  const int g  = blockIdx.x;
  const int which = blockIdx.y;
  const int hc = threadIdx.x;
  const float* __restrict__ w1 = which ? rw1 : lw1;
  float h = 0.f;
  if (g <= GBIN) {
    const float tt = (float)g * DELTA * STEP_INV;
    const int i0 = (int)floorf(tt);
    float z = 0.f;
#pragma unroll
    for (int k = 0; k < 2; ++k) {
      const int ii = i0 + k;
      if (ii >= 1 && ii <= 50) {
        const float diff = tt - (float)ii;
        const float a = diff + 1.f, b = 1.f - diff;
        if (a > 0.f && b > 0.f) {
          const float val = K0C * __expf(-1.f / a - 1.f / b);
          z += val * w1[(ii - 1) * HDIM + hc];
        }
      }
    }
    h = actc * z / (1.f + __expf(-z)) * INV_SQRT_H;
  }
  _Float16* __restrict__ H = which ? Hr : Hl;
  H[(size_t)g * HDIM + hc] = (_Float16)h;
}

// ---------------- K1b: W2 -> W2T[n][k] fp16 ----------------
__global__ __launch_bounds__(256) void k_w2t(
    const float* __restrict__ lw2, const float* __restrict__ rw2,
    _Float16* __restrict__ w2t) {
  const int gid = blockIdx.x * 256 + threadIdx.x;
  if (gid >= 64 * NC) return;
  const int k2 = gid / NC;
  const int n  = gid - k2 * NC;
  float a, b;
  if (n < NC1) {
    a = lw2[(size_t)(2 * k2) * NC1 + n];
    b = lw2[(size_t)(2 * k2 + 1) * NC1 + n];
  } else {
    const int m = n - NC1;
    a = rw2[(size_t)(2 * k2) * 3584 + m];
    b = rw2[(size_t)(2 * k2 + 1) * 3584 + m];
  }
  h2 p; p[0] = (_Float16)a; p[1] = (_Float16)b;
  *(h2*)(w2t + (size_t)n * HDIM + 2 * k2) = p;
}

// ---------------- K1c: LUT build via MFMA GEMM ----------------
__global__ __launch_bounds__(256) void k_lutm(
    const _Float16* __restrict__ Hl, const _Float16* __restrict__ Hr,
    const _Float16* __restrict__ w2t, _Float16* __restrict__ lut) {
  const int tid = threadIdx.x;
  const int nt = blockIdx.y * 4 + (tid >> 6);   // 0..259
  const int mt = blockIdx.x;                     // 0..128
  const int l  = tid & 63;
  const int rc = l & 15;
  const int kg = (l >> 4) * 8;
  const _Float16* __restrict__ Ap =
      ((nt < 36) ? Hl : Hr) + (size_t)(mt * 16 + rc) * HDIM + kg;
  const _Float16* __restrict__ Bp = w2t + (size_t)(nt * 16 + rc) * HDIM + kg;
  f32x4 acc = {0.f, 0.f, 0.f, 0.f};
#pragma unroll
  for (int kc = 0; kc < 4; ++kc) {
    h8 a = *(const h8*)(Ap + kc * 32);
    h8 b = *(const h8*)(Bp + kc * 32);
    acc = __builtin_amdgcn_mfma_f32_16x16x32_f16(a, b, acc, 0, 0, 0);
  }
#pragma unroll
  for (int r = 0; r < 4; ++r) {
    const int g = mt * 16 + (l >> 4) * 4 + r;
    if (g <= GBIN) lut[(size_t)g * NC + nt * 16 + rc] = (_Float16)acc[r];
  }
}

// ---------------- K2: per-edge bin/frac + histogram; zero inactive outputs ----------------
__global__ void k_edge(const int* __restrict__ ei, const float* __restrict__ pos,
                       float* __restrict__ out, int* __restrict__ bin_e,
                       float* __restrict__ f_e, int* __restrict__ cnt) {
  const int e = blockIdx.x * 256 + threadIdx.x;
  if (e >= NE) return;
  const int rec = ei[e], lig = ei[NE + e];
  const float ax = pos[lig * 3 + 0] - pos[rec * 3 + 0];
  const float ay = pos[lig * 3 + 1] - pos[rec * 3 + 1];
  const float az = pos[lig * 3 + 2] - pos[rec * 3 + 2];
  const float d = sqrtf(ax * ax + ay * ay + az * az);
  if (d > 0.f && d < 5.0f) {
    const float tf = d * INV_DELTA;
    int b = (int)tf;
    if (b > GBIN - 1) b = GBIN - 1;
    bin_e[e] = b;
    f_e[e] = tf - (float)b;
    atomicAdd(&cnt[b], 1);
  } else {
    bin_e[e] = -1;
    float* o = out + (size_t)e * 20;
#pragma unroll
    for (int i2 = 0; i2 < 20; ++i2) o[i2] = 0.f;
  }
}

// ---------------- K3a: scan + chunk-table emission (single block) ----------------
__global__ void k_scan(const int* __restrict__ cnt, int* __restrict__ offs,
                       int* __restrict__ woff, int* __restrict__ chunk_bin,
                       int* __restrict__ chunk_start, int* __restrict__ nch) {
  __shared__ int lds[256];
  const int t = threadIdx.x;
  int loc[8];
  int s = 0;
#pragma unroll
  for (int i = 0; i < 8; ++i) { loc[i] = cnt[t * 8 + i]; s += loc[i]; }
  lds[t] = s;
  __syncthreads();
  for (int o = 1; o < 256; o <<= 1) {
    int v = 0;
    if (t >= o) v = lds[t - o];
    __syncthreads();
    lds[t] += v;
    __syncthreads();
  }
  int run = lds[t] - s;
  int runs[8];
#pragma unroll
  for (int i = 0; i < 8; ++i) {
    runs[i] = run;
    offs[t * 8 + i] = run;
    woff[t * 8 + i] = run;
    run += loc[i];
  }
  if (t == 255) offs[GBIN] = run;

  int ccnt[8];
  int csum = 0;
#pragma unroll
  for (int i = 0; i < 8; ++i) { ccnt[i] = (loc[i] + 31) >> 5; csum += ccnt[i]; }
  __syncthreads();
  lds[t] = csum;
  __syncthreads();
  for (int o = 1; o < 256; o <<= 1) {
    int v = 0;
    if (t >= o) v = lds[t - o];
    __syncthreads();
    lds[t] += v;
    __syncthreads();
  }
  int crun = lds[t] - csum;
#pragma unroll
  for (int i = 0; i < 8; ++i) {
    for (int c = 0; c < ccnt[i]; ++c) {
      chunk_bin[crun]   = t * 8 + i;
      chunk_start[crun] = runs[i] + c * 32;
      ++crun;
    }
  }
  if (t == 255) nch[0] = lds[255];
}

// ---------------- K3b: counting-sort scatter ----------------
__global__ void k_scatter(const int* __restrict__ bin_e, int* __restrict__ woff,
                          int* __restrict__ sorted) {
  const int e = blockIdx.x * 256 + threadIdx.x;
  if (e >= NE) return;
  const int b = bin_e[e];
  if (b >= 0) {
    const int p = atomicAdd(&woff[b], 1);
    sorted[p] = e;
  }
}

// ---------------- K4: epilogue: 32-edge chunk / 128 threads; pair-interleaved fp16 LDS ----
// LDS pair n = (W0[n], W1[n]) at WP[2n] (16640 B). The per-edge lerp is folded into
// fdot2(pair, (q*(1-f), q*f)) with fp32 accumulate -> half the LDS reads, single acc set.
__global__ __launch_bounds__(128) void k_epi(
    const _Float16* __restrict__ lut, const int* __restrict__ chunk_bin,
    const int* __restrict__ chunk_start, const int* __restrict__ offs,
    const int* __restrict__ sorted, const float* __restrict__ f_e,
    const int* __restrict__ ei, const float* __restrict__ pos,
    const float* __restrict__ x, float* __restrict__ out,
    const int* __restrict__ nch) {
  __shared__ __fp16 WP[2 * NC];        // 16640 B
  const int bid = blockIdx.x;
  if (bid >= nch[0]) return;
  const int b     = chunk_bin[bid];
  const int start = chunk_start[bid];
  const int end0  = offs[b + 1];
  const int end   = (start + 32 < end0) ? (start + 32) : end0;
  const int tid = threadIdx.x;
  {  // stage: interleave rows b, b+1 into pairs
    const hp8* r0 = (const hp8*)(lut + (size_t)b * NC);
    const hp8* r1 = (const hp8*)(lut + (size_t)(b + 1) * NC);
    hp8* dst = (hp8*)WP;
    for (int i = tid; i < NC / 8; i += 128) {
      hp8 a = r0[i], c = r1[i];
      dst[2 * i]     = __builtin_shufflevector(a, c, 0, 8, 1, 9, 2, 10, 3, 11);
      dst[2 * i + 1] = __builtin_shufflevector(a, c, 4, 12, 5, 13, 6, 14, 7, 15);
    }
  }
  __syncthreads();
  const int s  = tid & 3;
  const int qb = (tid & 63) & ~3;
  const int slot = start + (tid >> 2);
  if (slot >= end) return;

  const int e = sorted[slot];
  const float f = f_e[e];
  const float fm = 1.f - f;
  const int rec = ei[e], lig = ei[NE + e];
  const float ax = pos[lig * 3 + 0] - pos[rec * 3 + 0];
  const float ay = pos[lig * 3 + 1] - pos[rec * 3 + 1];
  const float az = pos[lig * 3 + 2] - pos[rec * 3 + 2];
  const float d = sqrtf(ax * ax + ay * ay + az * az);
  const float inv = SQ3C / fmaxf(d, 1e-12f);
  const float sh0 = ax * inv, sh1 = ay * inv, sh2 = az * inv;

  // ---- lig features ----
  float s1[16], v1[24];
  {
    const float4* xl = (const float4*)(x + (size_t)lig * 40);
#pragma unroll
    for (int j = 0; j < 4; ++j) {
      float4 v = xl[j];
      s1[j * 4 + 0] = v.x; s1[j * 4 + 1] = v.y; s1[j * 4 + 2] = v.z; s1[j * 4 + 3] = v.w;
    }
#pragma unroll
    for (int j = 0; j < 6; ++j) {
      float4 v = xl[4 + j];
      v1[j * 4 + 0] = v.x; v1[j * 4 + 1] = v.y; v1[j * 4 + 2] = v.z; v1[j * 4 + 3] = v.w;
    }
  }
  float vs[8];
#pragma unroll
  for (int u = 0; u < 8; ++u)
    vs[u] = (v1[u * 3] * sh0 + v1[u * 3 + 1] * sh1 + v1[u * 3 + 2] * sh2) * INV_SQ3;

  // ---- layer 1: sa (lane owns w = 4s..4s+3); lerp folded in fdot2 ----
  float A[4] = {0.f, 0.f, 0.f, 0.f};
#pragma unroll
  for (int u = 0; u < 16; ++u) {   // W000 @ 0
    hp8 w = *(const hp8*)(WP + 2 * (u * 16 + s * 4));
    hp2 sp = pk2(s1[u] * fm, s1[u] * f);
    A[0] = fdot2f(mkh2(w[0], w[1]), sp, A[0]);
    A[1] = fdot2f(mkh2(w[2], w[3]), sp, A[1]);
    A[2] = fdot2f(mkh2(w[4], w[5]), sp, A[2]);
    A[3] = fdot2f(mkh2(w[6], w[7]), sp, A[3]);
  }
#pragma unroll
  for (int u = 0; u < 8; ++u) {    // W110 @ 448
    hp8 w = *(const hp8*)(WP + 2 * (448 + u * 16 + s * 4));
    hp2 sp = pk2(vs[u] * fm, vs[u] * f);
    A[0] = fdot2f(mkh2(w[0], w[1]), sp, A[0]);
    A[1] = fdot2f(mkh2(w[2], w[3]), sp, A[1]);
    A[2] = fdot2f(mkh2(w[4], w[5]), sp, A[2]);
    A[3] = fdot2f(mkh2(w[6], w[7]), sp, A[3]);
  }
  const float sa0 = C0_1F * A[0];
  const float sa1 = C0_1F * A[1];
  const float sa2 = C0_1F * A[2];
  const float sa3 = C0_1F * A[3];

  // ---- layer 1: va (lane owns w = 2s, 2s+1) ----
  float vaA0, vaA1, vaA2, vaB0, vaB1, vaB2;
  {
    float cA = 0.f, cB = 0.f;
#pragma unroll
    for (int u = 0; u < 16; ++u) {  // W011 @ 256
      hp4 w = *(const hp4*)(WP + 2 * (256 + u * 8 + s * 2));
      hp2 sp = pk2(s1[u] * fm, s1[u] * f);
      cA = fdot2f(mkh2(w[0], w[1]), sp, cA);
      cB = fdot2f(mkh2(w[2], w[3]), sp, cB);
    }
    float tAx = 0.f, tAy = 0.f, tAz = 0.f, tBx = 0.f, tBy = 0.f, tBz = 0.f;
#pragma unroll
    for (int u = 0; u < 8; ++u) {   // W101 @ 384
      hp4 w = *(const hp4*)(WP + 2 * (384 + u * 8 + s * 2));
      hp2 px = pk2(v1[u * 3] * fm,     v1[u * 3] * f);
      hp2 py = pk2(v1[u * 3 + 1] * fm, v1[u * 3 + 1] * f);
      hp2 pz = pk2(v1[u * 3 + 2] * fm, v1[u * 3 + 2] * f);
      hp2 pa = mkh2(w[0], w[1]);
      hp2 pb = mkh2(w[2], w[3]);
      tAx = fdot2f(pa, px, tAx); tAy = fdot2f(pa, py, tAy); tAz = fdot2f(pa, pz, tAz);
      tBx = fdot2f(pb, px, tBx); tBy = fdot2f(pb, py, tBy); tBz = fdot2f(pb, pz, tBz);
    }
    vaA0 = C1_1_OS3F * (cA * sh0 + tAx);
    vaA1 = C1_1_OS3F * (cA * sh1 + tAy);
    vaA2 = C1_1_OS3F * (cA * sh2 + tAz);
    vaB0 = C1_1_OS3F * (cB * sh0 + tBx);
    vaB1 = C1_1_OS3F * (cB * sh1 + tBy);
    vaB2 = C1_1_OS3F * (cB * sh2 + tBz);
  }

  // ---- quad allgather ----
  float saF[16];
#pragma unroll
  for (int k = 0; k < 16; ++k) {
    const float v = ((k & 3) == 0) ? sa0 : ((k & 3) == 1) ? sa1 : ((k & 3) == 2) ? sa2 : sa3;
    saF[k] = __shfl(v, qb + (k >> 2), 64);
  }
  float vaF[24];
#pragma unroll
  for (int w = 0; w < 8; ++w) {
    const int src = qb + (w >> 1);
    const float x0 = (w & 1) ? vaB0 : vaA0;
    const float x1 = (w & 1) ? vaB1 : vaA1;
    const float x2 = (w & 1) ? vaB2 : vaA2;
    vaF[w * 3 + 0] = __shfl(x0, src, 64);
    vaF[w * 3 + 1] = __shfl(x1, src, 64);
    vaF[w * 3 + 2] = __shfl(x2, src, 64);
  }

  // ---- rec features: lane's v-subset ----
  const float* xr = x + (size_t)rec * 40;
  const float sbl0 = xr[s],      sbl1 = xr[4 + s];
  const float sbl2 = xr[8 + s],  sbl3 = xr[12 + s];
  const float vbA0 = xr[16 + s * 3 + 0], vbA1 = xr[16 + s * 3 + 1], vbA2 = xr[16 + s * 3 + 2];
  const float vbB0 = xr[16 + (s + 4) * 3 + 0], vbB1 = xr[16 + (s + 4) * 3 + 1], vbB2 = xr[16 + (s + 4) * 3 + 2];

  float oe[20];

  // ===== layer 2: s_out, single pass (lerp in fdot2) =====
  {
    float so[8];
#pragma unroll
    for (int w = 0; w < 8; ++w) so[w] = 0.f;
    // W000 @ 576: [u:16][v:16][w:8], v = vv*4+s
#pragma unroll
    for (int u = 0; u < 16; ++u) {
      const float su = saF[u];
      const __fp16* rp = WP + 2 * (576 + u * 128 + s * 8);
#pragma unroll
      for (int vv = 0; vv < 4; ++vv) {
        const float q = su * ((vv == 0) ? sbl0 : (vv == 1) ? sbl1 : (vv == 2) ? sbl2 : sbl3);
        hp2 qp = pk2(q * fm, q * f);
        hp8 wa = *(const hp8*)(rp + 2 * (vv * 32));
        hp8 wb = *(const hp8*)(rp + 2 * (vv * 32) + 8);
        so[0] = fdot2f(mkh2(wa[0], wa[1]), qp, so[0]);
        so[1] = fdot2f(mkh2(wa[2], wa[3]), qp, so[1]);
        so[2] = fdot2f(mkh2(wa[4], wa[5]), qp, so[2]);
        so[3] = fdot2f(mkh2(wa[6], wa[7]), qp, so[3]);
        so[4] = fdot2f(mkh2(wb[0], wb[1]), qp, so[4]);
        so[5] = fdot2f(mkh2(wb[2], wb[3]), qp, so[5]);
        so[6] = fdot2f(mkh2(wb[4], wb[5]), qp, so[6]);
        so[7] = fdot2f(mkh2(wb[6], wb[7]), qp, so[7]);
      }
    }
    // W110 @ 3648: [u:8][v:8][w:8], v = vv*4+s
#pragma unroll
    for (int u = 0; u < 8; ++u) {
      const float a0 = vaF[u * 3], a1 = vaF[u * 3 + 1], a2 = vaF[u * 3 + 2];
      const __fp16* rp = WP + 2 * (3648 + u * 64 + s * 8);
#pragma unroll
      for (int vv = 0; vv < 2; ++vv) {
        const float b0v = vv ? vbB0 : vbA0;
        const float b1v = vv ? vbB1 : vbA1;
        const float b2v = vv ? vbB2 : vbA2;
        const float dd = (a0 * b0v + a1 * b1v + a2 * b2v) * INV_SQ3;
        hp2 qp = pk2(dd * fm, dd * f);
        hp8 wa = *(const hp8*)(rp + 2 * (vv * 32));
        hp8 wb = *(const hp8*)(rp + 2 * (vv * 32) + 8);
        so[0] = fdot2f(mkh2(wa[0], wa[1]), qp, so[0]);
        so[1] = fdot2f(mkh2(wa[2], wa[3]), qp, so[1]);
        so[2] = fdot2f(mkh2(wa[4], wa[5]), qp, so[2]);
        so[3] = fdot2f(mkh2(wa[6], wa[7]), qp, so[3]);
        so[4] = fdot2f(mkh2(wb[0], wb[1]), qp, so[4]);
        so[5] = fdot2f(mkh2(wb[2], wb[3]), qp, so[5]);
        so[6] = fdot2f(mkh2(wb[4], wb[5]), qp, so[6]);
        so[7] = fdot2f(mkh2(wb[6], wb[7]), qp, so[7]);
      }
    }
#pragma unroll
    for (int w = 0; w < 8; ++w) oe[w] = C0_2F * so[w];
  }

  // ===== layer 2: v_out, single pass =====
  {
    float uo[12];
#pragma unroll
    for (int w = 0; w < 12; ++w) uo[w] = 0.f;
    // W011 @ 2624: [u:16][v:8][w:4], v = vv*4+s
#pragma unroll
    for (int u = 0; u < 16; ++u) {
      const float su = saF[u];
      const __fp16* rp = WP + 2 * (2624 + u * 32 + s * 4);
#pragma unroll
      for (int vv = 0; vv < 2; ++vv) {
        const float q0 = su * (vv ? vbB0 : vbA0);
        const float q1 = su * (vv ? vbB1 : vbA1);
        const float q2 = su * (vv ? vbB2 : vbA2);
        hp2 q0p = pk2(q0 * fm, q0 * f);
        hp2 q1p = pk2(q1 * fm, q1 * f);
        hp2 q2p = pk2(q2 * fm, q2 * f);
        hp8 w = *(const hp8*)(rp + 2 * (vv * 16));
        hp2 p0 = mkh2(w[0], w[1]);
        hp2 p1 = mkh2(w[2], w[3]);
        hp2 p2 = mkh2(w[4], w[5]);
        hp2 p3 = mkh2(w[6], w[7]);
        uo[0] = fdot2f(p0, q0p, uo[0]); uo[1]  = fdot2f(p0, q1p, uo[1]);  uo[2]  = fdot2f(p0, q2p, uo[2]);
        uo[3] = fdot2f(p1, q0p, uo[3]); uo[4]  = fdot2f(p1, q1p, uo[4]);  uo[5]  = fdot2f(p1, q2p, uo[5]);
        uo[6] = fdot2f(p2, q0p, uo[6]); uo[7]  = fdot2f(p2, q1p, uo[7]);  uo[8]  = fdot2f(p2, q2p, uo[8]);
        uo[9] = fdot2f(p3, q0p, uo[9]); uo[10] = fdot2f(p3, q1p, uo[10]); uo[11] = fdot2f(p3, q2p, uo[11]);
      }
    }
    // W101 @ 3136: [u:8][v:16][w:4], v = vv*4+s
#pragma unroll
    for (int u = 0; u < 8; ++u) {
      const float a0 = vaF[u * 3], a1 = vaF[u * 3 + 1], a2 = vaF[u * 3 + 2];
      const __fp16* rp = WP + 2 * (3136 + u * 64 + s * 4);
#pragma unroll
      for (int vv = 0; vv < 4; ++vv) {
        const float sbv = (vv == 0) ? sbl0 : (vv == 1) ? sbl1 : (vv == 2) ? sbl2 : sbl3;
        const float q0 = a0 * sbv, q1 = a1 * sbv, q2 = a2 * sbv;
        hp2 q0p = pk2(q0 * fm, q0 * f);
        hp2 q1p = pk2(q1 * fm, q1 * f);
        hp2 q2p = pk2(q2 * fm, q2 * f);
        hp8 w = *(const hp8*)(rp + 2 * (vv * 16));
        hp2 p0 = mkh2(w[0], w[1]);
        hp2 p1 = mkh2(w[2], w[3]);
        hp2 p2 = mkh2(w[4], w[5]);
        hp2 p3 = mkh2(w[6], w[7]);
        uo[0] = fdot2f(p0, q0p, uo[0]); uo[1]  = fdot2f(p0, q1p, uo[1]);  uo[2]  = fdot2f(p0, q2p, uo[2]);
        uo[3] = fdot2f(p1, q0p, uo[3]); uo[4]  = fdot2f(p1, q1p, uo[4]);  uo[5]  = fdot2f(p1, q2p, uo[5]);
        uo[6] = fdot2f(p2, q0p, uo[6]); uo[7]  = fdot2f(p2, q1p, uo[7]);  uo[8]  = fdot2f(p2, q2p, uo[8]);
        uo[9] = fdot2f(p3, q0p, uo[9]); uo[10] = fdot2f(p3, q1p, uo[10]); uo[11] = fdot2f(p3, q2p, uo[11]);
      }
    }
#pragma unroll
    for (int w = 0; w < 12; ++w) oe[8 + w] = C1_2_OS3F * uo[w];
  }

  // ---- quad butterfly reduce + store ----
#pragma unroll
  for (int w = 0; w < 20; ++w) {
    oe[w] += __shfl_xor(oe[w], 1, 64);
    oe[w] += __shfl_xor(oe[w], 2, 64);
  }
  if (s == 0) {
    float4* op = (float4*)(out + (size_t)e * 20);
#pragma unroll
    for (int j = 0; j < 5; ++j) {
      float4 o4;
      o4.x = oe[j * 4 + 0]; o4.y = oe[j * 4 + 1];
      o4.z = oe[j * 4 + 2]; o4.w = oe[j * 4 + 3];
      op[j] = o4;
    }
  }
}

// ---------------- host ----------------
extern "C" void kernel_launch(void* const* d_in, const int* in_sizes, int n_in,
                              void* d_out, int out_size, void* d_ws, size_t ws_size,
                              hipStream_t stream) {
  const int*   ei  = (const int*)d_in[0];
  const float* pos = (const float*)d_in[1];
  const float* x   = (const float*)d_in[2];
  const float* lw1 = (const float*)d_in[3];
  const float* lw2 = (const float*)d_in[4];
  const float* rw1 = (const float*)d_in[5];
  const float* rw2 = (const float*)d_in[6];
  float* out = (float*)d_out;
  char*  ws  = (char*)d_ws;

  size_t o = 0;
  _Float16* lut = (_Float16*)(ws + o); o += (size_t)NLUT * NC * 2;
  o = (o + 15) & ~(size_t)15;
  _Float16* Hl  = (_Float16*)(ws + o); o += (size_t)MPAD * HDIM * 2;
  _Float16* Hr  = (_Float16*)(ws + o); o += (size_t)MPAD * HDIM * 2;
  _Float16* w2t = (_Float16*)(ws + o); o += (size_t)NC * HDIM * 2;
  o = (o + 15) & ~(size_t)15;
  int*   bin_e = (int*)(ws + o);  o += (size_t)NE * 4;
  float* f_e   = (float*)(ws + o); o += (size_t)NE * 4;
  int*   cnt   = (int*)(ws + o);  o += (size_t)GBIN * 4;
  int*   offs  = (int*)(ws + o);  o += (size_t)(GBIN + 1) * 4 + 12;
  int*   woff  = (int*)(ws + o);  o += (size_t)GBIN * 4;
  int*   sorted = (int*)(ws + o); o += (size_t)NE * 4;
  int*   chunk_bin   = (int*)(ws + o); o += (size_t)NCHMAX * 4;
  int*   chunk_start = (int*)(ws + o); o += (size_t)NCHMAX * 4;
  int*   nch = (int*)(ws + o); o += 16;

  // ACT_C on host (runs at capture time, not in the timed graph)
  double ssum = 0.0;
  const double dz = 20.0 / 40000.0;
  for (int i = 0; i <= 40000; ++i) {
    const double z = -10.0 + dz * (double)i;
    const double sil = z / (1.0 + exp(-z));
    const double phi = exp(-0.5 * z * z) / sqrt(2.0 * M_PI);
    ssum += sil * sil * phi;
  }
  const float actc = (float)(1.0 / sqrt(ssum * dz));
  const float k0c  = (float)(1.14136 * exp(2.0));

  hipMemsetAsync(cnt, 0, GBIN * 4, stream);
  k_hprep<<<dim3(MPAD, 2), 128, 0, stream>>>(lw1, rw1, actc, k0c, Hl, Hr);
  k_w2t<<<(64 * NC + 255) / 256, 256, 0, stream>>>(lw2, rw2, w2t);
  k_lutm<<<dim3(129, 65), 256, 0, stream>>>(Hl, Hr, w2t, lut);
  k_edge<<<(NE + 255) / 256, 256, 0, stream>>>(ei, pos, out, bin_e, f_e, cnt);
  k_scan<<<1, 256, 0, stream>>>(cnt, offs, woff, chunk_bin, chunk_start, nch);
  k_scatter<<<(NE + 255) / 256, 256, 0, stream>>>(bin_e, woff, sorted);
  k_epi<<<NCHMAX, 128, 0, stream>>>(lut, chunk_bin, chunk_start, offs, sorted, f_e,
                                    ei, pos, x, out, nch);
}